// Round 10
// baseline (485.766 us; speedup 1.0000x reference)
//
#include <hip/hip_runtime.h>
#include <hip/hip_bf16.h>
#include <cstddef>

// Problem constants (fixed-shape problem)
constexpr int N_NODES = 50000;
constexpr int N_EDGES = 800000;
constexpr int IN_DIM  = 128;
constexpr int HID     = 64;
constexpr int HEADS   = 4;
constexpr int F1      = HEADS * HID;  // 256
constexpr int EMB     = 128;
constexpr int N_GRAPHS = 64;

constexpr int DEG_BLOCKS   = (N_EDGES + 255) / 256;  // 3125
constexpr int SCAN_BLOCKS  = (N_NODES + 255) / 256;  // 196
// per-head W1 fragment size (NT=4, KK=4): 4*4*64*8 bf16 elements
constexpr int W1_FRAG = 4 * 4 * 64 * 8;              // 8192
// Fused-kernel LDS row stride (f32): 128 cols + 4 pad. 132 mod 32 = 4 ->
// phase-2 row starts 2-way bank-aliased (free, m136). 32*132*4 = 16.9 KB
// -> 9 workgroups/CU x 2 waves = 18 waves/CU (was 8 with the 268-wide tile).
constexpr int LDP = 132;

typedef __bf16 bf16x8 __attribute__((ext_vector_type(8)));
typedef float  f32x4  __attribute__((ext_vector_type(4)));

__device__ __forceinline__ float lrelu(float x) { return x > 0.f ? x : 0.2f * x; }
__device__ __forceinline__ float eluf(float x)  { return x > 0.f ? x : expm1f(x); }

// ---------------------------------------------------------------------------
// Pack a [K x 16*NT] submatrix of B (leading dim ld, origin col0) into
// per-lane MFMA B-fragments, split hi/lo bf16.
// ---------------------------------------------------------------------------
__device__ __forceinline__ void pack_frag(const float* __restrict__ B,
                                          __bf16* __restrict__ hi,
                                          __bf16* __restrict__ lo,
                                          int pblk, int NT, int KK, int ld, int col0) {
    const int gid = pblk * 256 + threadIdx.x;
    if (gid >= NT * KK * 64) return;
    const int lane = gid & 63;
    const int rem  = gid >> 6;
    const int kk   = rem % KK;
    const int t    = rem / KK;
    const int n    = col0 + t * 16 + (lane & 15);
    const int k0   = kk * 32 + (lane >> 4) * 8;
#pragma unroll
    for (int j = 0; j < 8; j++) {
        const float v = B[(size_t)(k0 + j) * ld + n];
        const __bf16 h = (__bf16)v;
        hi[(size_t)gid * 8 + j] = h;
        lo[(size_t)gid * 8 + j] = (__bf16)(v - (float)h);
    }
}

// ---------------------------------------------------------------------------
// prep: [deg histogram | pack W1 per-head | pack W2] by block range.
// ---------------------------------------------------------------------------
__global__ __launch_bounds__(256) void prep_kernel(const int* __restrict__ ei,
                                                   int* __restrict__ deg,
                                                   const float* __restrict__ W1,
                                                   __bf16* __restrict__ B1h,
                                                   __bf16* __restrict__ B1l,
                                                   const float* __restrict__ W2,
                                                   __bf16* __restrict__ B2h,
                                                   __bf16* __restrict__ B2l) {
    const int b = blockIdx.x;
    if (b < DEG_BLOCKS) {
        const int e = b * 256 + threadIdx.x;
        if (e < N_EDGES) atomicAdd(&deg[ei[N_EDGES + e]], 1);
        return;
    }
    const int pb = b - DEG_BLOCKS;
    if (pb < 16) {
        const int head = pb >> 2;
        pack_frag(W1, B1h + head * W1_FRAG, B1l + head * W1_FRAG,
                  pb & 3, 4, 4, F1, head * HID);
    } else {
        pack_frag(W2, B2h, B2l, pb - 16, 8, 8, EMB, 0);
    }
}

// ---------------------------------------------------------------------------
// 3-phase parallel scan (deg -> off); phase C also zeroes cur.
// ---------------------------------------------------------------------------
__global__ __launch_bounds__(256) void scanA_kernel(const int* __restrict__ deg,
                                                    int* __restrict__ off,
                                                    int* __restrict__ partial, int N) {
    __shared__ int sm[256];
    const int t = threadIdx.x;
    const int i = blockIdx.x * 256 + t;
    const int v = (i < N) ? deg[i] : 0;
    sm[t] = v;
    __syncthreads();
    int val = v;
#pragma unroll
    for (int o = 1; o < 256; o <<= 1) {
        const int add = (t >= o) ? sm[t - o] : 0;
        __syncthreads();
        val += add;
        sm[t] = val;
        __syncthreads();
    }
    if (i < N) off[i] = val - v;
    if (t == 255) partial[blockIdx.x] = val;
}

__global__ __launch_bounds__(256) void scanB_kernel(int* __restrict__ partial,
                                                    int* __restrict__ off_last) {
    __shared__ int sm[256];
    const int t = threadIdx.x;
    const int v = (t < SCAN_BLOCKS) ? partial[t] : 0;
    sm[t] = v;
    __syncthreads();
    int val = v;
#pragma unroll
    for (int o = 1; o < 256; o <<= 1) {
        const int add = (t >= o) ? sm[t - o] : 0;
        __syncthreads();
        val += add;
        sm[t] = val;
        __syncthreads();
    }
    if (t < SCAN_BLOCKS) partial[t] = val - v;
    if (t == SCAN_BLOCKS - 1) *off_last = val;
}

__global__ __launch_bounds__(256) void scanC_kernel(int* __restrict__ off,
                                                    const int* __restrict__ partial,
                                                    int* __restrict__ cur, int N) {
    const int i = blockIdx.x * 256 + threadIdx.x;
    if (i < N) {
        off[i] += partial[blockIdx.x];
        cur[i] = 0;
    }
}

// ---------------------------------------------------------------------------
// gemm1: as1/ad1 = alpha-logits of (x @ W1). No C store.
// ---------------------------------------------------------------------------
__global__ __launch_bounds__(256) void gemm1_kernel(
        const float* __restrict__ A, const __bf16* __restrict__ Bh,
        const __bf16* __restrict__ Bl, const float* __restrict__ avs,
        const float* __restrict__ avd, float* __restrict__ as_out,
        float* __restrict__ ad_out, int M) {
    constexpr int NT = F1 / 16, KK = IN_DIM / 32, NH = HEADS;
    constexpr int Ncols = NT * 16;
    constexpr int K = KK * 32;
    const int tid  = threadIdx.x;
    const int wave = tid >> 6, lane = tid & 63;
    const int quad = lane >> 4, l16 = lane & 15;
    const int rowA = min((int)blockIdx.x * 64 + wave * 16 + l16, M - 1);

    f32x4 acc[NT];
#pragma unroll
    for (int t = 0; t < NT; t++) acc[t] = (f32x4){0.f, 0.f, 0.f, 0.f};

    for (int kk = 0; kk < KK; kk++) {
        const int k0 = kk * 32 + quad * 8;
        float a8[8];
        *(float4*)&a8[0] = *(const float4*)&A[(size_t)rowA * K + k0];
        *(float4*)&a8[4] = *(const float4*)&A[(size_t)rowA * K + k0 + 4];
        bf16x8 ah, al;
#pragma unroll
        for (int j = 0; j < 8; j++) {
            const __bf16 h = (__bf16)a8[j];
            ah[j] = h;
            al[j] = (__bf16)(a8[j] - (float)h);
        }
#pragma unroll
        for (int t = 0; t < NT; t++) {
            const size_t bi = ((size_t)(t * KK + kk) * 64 + lane) * 8;
            bf16x8 bhv = *(const bf16x8*)&Bh[bi];
            bf16x8 blv = *(const bf16x8*)&Bl[bi];
            acc[t] = __builtin_amdgcn_mfma_f32_16x16x32_bf16(ah, bhv, acc[t], 0, 0, 0);
            acc[t] = __builtin_amdgcn_mfma_f32_16x16x32_bf16(al, bhv, acc[t], 0, 0, 0);
            acc[t] = __builtin_amdgcn_mfma_f32_16x16x32_bf16(ah, blv, acc[t], 0, 0, 0);
        }
    }

    const int rowS = blockIdx.x * 64 + wave * 16 + quad * 4;
#pragma unroll
    for (int r = 0; r < 4; r++) {
        float ps[NH], pd[NH];
#pragma unroll
        for (int h = 0; h < NH; h++) { ps[h] = 0.f; pd[h] = 0.f; }
#pragma unroll
        for (int t = 0; t < NT; t++) {
            const int h = (t * 16) / (Ncols / NH);
            const int col = t * 16 + l16;
            ps[h] += acc[t][r] * avs[col];
            pd[h] += acc[t][r] * avd[col];
        }
#pragma unroll
        for (int o = 1; o < 16; o <<= 1) {
#pragma unroll
            for (int h = 0; h < NH; h++) {
                ps[h] += __shfl_xor(ps[h], o);
                pd[h] += __shfl_xor(pd[h], o);
            }
        }
        const int rr = rowS + r;
        if (l16 == 0 && rr < M) {
#pragma unroll
            for (int h = 0; h < NH; h++) {
                as_out[rr * NH + h] = ps[h];
                ad_out[rr * NH + h] = pd[h];
            }
        }
    }
}

// CSR scatter fused with layer-1 edge-weight computation (as1/ad1 ready).
__global__ __launch_bounds__(256) void scatter_w1_kernel(
        const int* __restrict__ ei, const int* __restrict__ off,
        int* __restrict__ cur, int* __restrict__ col, int* __restrict__ row,
        const float* __restrict__ as1, const float* __restrict__ ad1,
        float4* __restrict__ w4, int E) {
    const int e = blockIdx.x * 256 + threadIdx.x;
    if (e >= E) return;
    const int s = ei[e], d = ei[E + e];
    const int pos = atomicAdd(&cur[d], 1);
    const int slot = off[d] + pos;
    col[slot] = s;
    row[slot] = d;
    const float4 a = *(const float4*)&as1[s * HEADS];
    const float4 b = *(const float4*)&ad1[d * HEADS];
    float4 o;
    o.x = expf(lrelu(a.x + b.x));
    o.y = expf(lrelu(a.y + b.y));
    o.z = expf(lrelu(a.z + b.z));
    o.w = expf(lrelu(a.w + b.w));
    w4[slot] = o;
}

// Layer-2 edge weights (one exp per edge instead of 64).
__global__ __launch_bounds__(256) void w2_kernel(const int* __restrict__ col,
                                                 const int* __restrict__ row,
                                                 const float* __restrict__ as2,
                                                 const float* __restrict__ ad2,
                                                 float* __restrict__ w2, int E) {
    const int i = blockIdx.x * 256 + threadIdx.x;
    if (i >= E) return;
    w2[i] = expf(lrelu(as2[col[i]] + ad2[row[i]]));
}

// ---------------------------------------------------------------------------
// Layer-1 x-aggregation: one wave per dst node, scalarized uniform accesses,
// 4-edge unroll. aggx[node][head][:] = (sum_e w_e x[src_e]) / z_h.
// ---------------------------------------------------------------------------
__global__ __launch_bounds__(256) void agg1x_kernel(const int* __restrict__ off,
                                                    const int* __restrict__ col,
                                                    const float4* __restrict__ w4,
                                                    const float* __restrict__ x,
                                                    const float* __restrict__ as1,
                                                    const float* __restrict__ ad1,
                                                    float* __restrict__ aggx, int N) {
    const int w = __builtin_amdgcn_readfirstlane((blockIdx.x * 256 + threadIdx.x) >> 6);
    const int lane = threadIdx.x & 63;
    if (w >= N) return;

    float2 acc[HEADS];
    float z[HEADS];
#pragma unroll
    for (int h = 0; h < HEADS; h++) { acc[h] = make_float2(0.f, 0.f); z[h] = 0.f; }

    {   // self-loop
        const float4 asv = *(const float4*)&as1[w * HEADS];
        const float4 adv = *(const float4*)&ad1[w * HEADS];
        const float2 xv = *(const float2*)&x[(size_t)w * IN_DIM + lane * 2];
        float ws[HEADS] = {expf(lrelu(asv.x + adv.x)), expf(lrelu(asv.y + adv.y)),
                           expf(lrelu(asv.z + adv.z)), expf(lrelu(asv.w + adv.w))};
#pragma unroll
        for (int h = 0; h < HEADS; h++) {
            acc[h].x += ws[h] * xv.x; acc[h].y += ws[h] * xv.y; z[h] += ws[h];
        }
    }
    const int jb = off[w], je = off[w + 1];
    int j = jb;
    for (; j + 3 < je; j += 4) {
        const int s0 = col[j], s1 = col[j + 1], s2 = col[j + 2], s3 = col[j + 3];
        const float4 w0 = w4[j], w1 = w4[j + 1], w2 = w4[j + 2], w3 = w4[j + 3];
        const float2 v0 = *(const float2*)&x[(size_t)s0 * IN_DIM + lane * 2];
        const float2 v1 = *(const float2*)&x[(size_t)s1 * IN_DIM + lane * 2];
        const float2 v2 = *(const float2*)&x[(size_t)s2 * IN_DIM + lane * 2];
        const float2 v3 = *(const float2*)&x[(size_t)s3 * IN_DIM + lane * 2];
        acc[0].x += w0.x * v0.x + w1.x * v1.x + w2.x * v2.x + w3.x * v3.x;
        acc[0].y += w0.x * v0.y + w1.x * v1.y + w2.x * v2.y + w3.x * v3.y;
        acc[1].x += w0.y * v0.x + w1.y * v1.x + w2.y * v2.x + w3.y * v3.x;
        acc[1].y += w0.y * v0.y + w1.y * v1.y + w2.y * v2.y + w3.y * v3.y;
        acc[2].x += w0.z * v0.x + w1.z * v1.x + w2.z * v2.x + w3.z * v3.x;
        acc[2].y += w0.z * v0.y + w1.z * v1.y + w2.z * v2.y + w3.z * v3.y;
        acc[3].x += w0.w * v0.x + w1.w * v1.x + w2.w * v2.x + w3.w * v3.x;
        acc[3].y += w0.w * v0.y + w1.w * v1.y + w2.w * v2.y + w3.w * v3.y;
        z[0] += (w0.x + w1.x) + (w2.x + w3.x);
        z[1] += (w0.y + w1.y) + (w2.y + w3.y);
        z[2] += (w0.z + w1.z) + (w2.z + w3.z);
        z[3] += (w0.w + w1.w) + (w2.w + w3.w);
    }
    for (; j < je; j++) {
        const int s0 = col[j];
        const float4 w0 = w4[j];
        const float2 v0 = *(const float2*)&x[(size_t)s0 * IN_DIM + lane * 2];
        acc[0].x += w0.x * v0.x; acc[0].y += w0.x * v0.y; z[0] += w0.x;
        acc[1].x += w0.y * v0.x; acc[1].y += w0.y * v0.y; z[1] += w0.y;
        acc[2].x += w0.z * v0.x; acc[2].y += w0.z * v0.y; z[2] += w0.z;
        acc[3].x += w0.w * v0.x; acc[3].y += w0.w * v0.y; z[3] += w0.w;
    }
#pragma unroll
    for (int h = 0; h < HEADS; h++) {
        const float inv = 1.f / z[h];
        float2 o = make_float2(acc[h].x * inv, acc[h].y * inv);
        *(float2*)&aggx[((size_t)w * HEADS + h) * IN_DIM + lane * 2] = o;
    }
}

// ---------------------------------------------------------------------------
// FUSED layer-1-reconstruct + layer-2 GEMM, half-K LDS staging:
//   half 0: h cols 0..127 (heads 0,1) -> LDS -> acc2 += (kk 0..3)
//   half 1: h cols 128..255 (heads 2,3) -> LDS (reused) -> acc2 += (kk 4..7)
// LDS = 32 x 132 f32 = 16.9 KB -> 18 waves/CU (R9's 268-wide tile capped at 8).
// ---------------------------------------------------------------------------
__global__ __launch_bounds__(128) void gemm12_kernel(
        const float* __restrict__ aggx,
        const __bf16* __restrict__ B1h, const __bf16* __restrict__ B1l,
        const float* __restrict__ b1,
        const __bf16* __restrict__ B2h, const __bf16* __restrict__ B2l,
        const float* __restrict__ avs, const float* __restrict__ avd,
        float* __restrict__ g2, float* __restrict__ as_out,
        float* __restrict__ ad_out, int M) {
    __shared__ float sm[32 * LDP];
    const int tid  = threadIdx.x;
    const int wave = tid >> 6, lane = tid & 63;
    const int quad = lane >> 4, l16 = lane & 15;
    const int rowA = min((int)blockIdx.x * 32 + wave * 16 + l16, M - 1);

    f32x4 acc2[8];
#pragma unroll
    for (int t = 0; t < 8; t++) acc2[t] = (f32x4){0.f, 0.f, 0.f, 0.f};

#pragma unroll
    for (int half = 0; half < 2; half++) {
        // ---- phase 1: heads 2*half, 2*half+1 -> 128 cols ----
        f32x4 acc1[8];
#pragma unroll
        for (int i = 0; i < 8; i++) acc1[i] = (f32x4){0.f, 0.f, 0.f, 0.f};
#pragma unroll
        for (int hl = 0; hl < 2; hl++) {
            const int h = half * 2 + hl;
            const float* Arow = aggx + ((size_t)rowA * HEADS + h) * IN_DIM;
#pragma unroll
            for (int kk = 0; kk < 4; kk++) {
                const int k0 = kk * 32 + quad * 8;
                float a8[8];
                *(float4*)&a8[0] = *(const float4*)&Arow[k0];
                *(float4*)&a8[4] = *(const float4*)&Arow[k0 + 4];
                bf16x8 ah, al;
#pragma unroll
                for (int j = 0; j < 8; j++) {
                    const __bf16 hh = (__bf16)a8[j];
                    ah[j] = hh;
                    al[j] = (__bf16)(a8[j] - (float)hh);
                }
#pragma unroll
                for (int t = 0; t < 4; t++) {
                    const size_t bi = (size_t)h * W1_FRAG +
                                      ((size_t)(t * 4 + kk) * 64 + lane) * 8;
                    bf16x8 bhv = *(const bf16x8*)&B1h[bi];
                    bf16x8 blv = *(const bf16x8*)&B1l[bi];
                    acc1[hl*4+t] = __builtin_amdgcn_mfma_f32_16x16x32_bf16(ah, bhv, acc1[hl*4+t], 0, 0, 0);
                    acc1[hl*4+t] = __builtin_amdgcn_mfma_f32_16x16x32_bf16(al, bhv, acc1[hl*4+t], 0, 0, 0);
                    acc1[hl*4+t] = __builtin_amdgcn_mfma_f32_16x16x32_bf16(ah, blv, acc1[hl*4+t], 0, 0, 0);
                }
            }
        }
        // ELU(+b1) -> LDS (local col = hl*64 + t*16 + l16, global col += half*128)
        const int lrow = wave * 16 + quad * 4;
#pragma unroll
        for (int hl = 0; hl < 2; hl++) {
#pragma unroll
            for (int t = 0; t < 4; t++) {
                const int cl = hl * 64 + t * 16 + l16;
                const float bb = b1[half * 128 + cl];
#pragma unroll
                for (int r = 0; r < 4; r++) {
                    sm[(lrow + r) * LDP + cl] = eluf(acc1[hl*4+t][r] + bb);
                }
            }
        }
        __syncthreads();

        // ---- phase 2: consume this half's 4 K-blocks from LDS ----
        const int arow = (wave * 16 + l16) * LDP;
#pragma unroll
        for (int kk2 = 0; kk2 < 4; kk2++) {
            const int k0 = kk2 * 32 + quad * 8;
            float a8[8];
            *(float4*)&a8[0] = *(const float4*)&sm[arow + k0];
            *(float4*)&a8[4] = *(const float4*)&sm[arow + k0 + 4];
            bf16x8 ah, al;
#pragma unroll
            for (int j = 0; j < 8; j++) {
                const __bf16 hh = (__bf16)a8[j];
                ah[j] = hh;
                al[j] = (__bf16)(a8[j] - (float)hh);
            }
            const int kk = half * 4 + kk2;
#pragma unroll
            for (int t = 0; t < 8; t++) {
                const size_t bi = ((size_t)(t * 8 + kk) * 64 + lane) * 8;
                bf16x8 bhv = *(const bf16x8*)&B2h[bi];
                bf16x8 blv = *(const bf16x8*)&B2l[bi];
                acc2[t] = __builtin_amdgcn_mfma_f32_16x16x32_bf16(ah, bhv, acc2[t], 0, 0, 0);
                acc2[t] = __builtin_amdgcn_mfma_f32_16x16x32_bf16(al, bhv, acc2[t], 0, 0, 0);
                acc2[t] = __builtin_amdgcn_mfma_f32_16x16x32_bf16(ah, blv, acc2[t], 0, 0, 0);
            }
        }
        __syncthreads();  // LDS reuse fence before next half's writes
    }

    // store g2 + alpha2 logits (1 head)
    const int rowS = blockIdx.x * 32 + wave * 16 + quad * 4;
#pragma unroll
    for (int t = 0; t < 8; t++) {
#pragma unroll
        for (int r = 0; r < 4; r++) {
            const int rr = rowS + r;
            if (rr < M) g2[(size_t)rr * EMB + t * 16 + l16] = acc2[t][r];
        }
    }
#pragma unroll
    for (int r = 0; r < 4; r++) {
        float ps = 0.f, pd = 0.f;
#pragma unroll
        for (int t = 0; t < 8; t++) {
            const int c = t * 16 + l16;
            ps += acc2[t][r] * avs[c];
            pd += acc2[t][r] * avd[c];
        }
#pragma unroll
        for (int o = 1; o < 16; o <<= 1) {
            ps += __shfl_xor(ps, o);
            pd += __shfl_xor(pd, o);
        }
        const int rr = rowS + r;
        if (l16 == 0 && rr < M) {
            as_out[rr] = ps;
            ad_out[rr] = pd;
        }
    }
}

// ---------------------------------------------------------------------------
// Layer-2 aggregation: one wave per dst node, precomputed scalar weights.
// ---------------------------------------------------------------------------
__global__ __launch_bounds__(256) void agg2_kernel(const int* __restrict__ off,
                                                   const int* __restrict__ col,
                                                   const float* __restrict__ w2,
                                                   const float* __restrict__ g2,
                                                   const float* __restrict__ as2,
                                                   const float* __restrict__ ad2,
                                                   float* __restrict__ out2, int N) {
    const int w = __builtin_amdgcn_readfirstlane((blockIdx.x * 256 + threadIdx.x) >> 6);
    const int lane = threadIdx.x & 63;
    if (w >= N) return;

    float2 acc = make_float2(0.f, 0.f);
    float z = 0.f;
    {   // self-loop
        const float wt = expf(lrelu(as2[w] + ad2[w]));
        float2 hv = *(const float2*)&g2[(size_t)w * EMB + lane * 2];
        acc.x += wt * hv.x; acc.y += wt * hv.y;
        z += wt;
    }
    const int jb = off[w], je = off[w + 1];
    int j = jb;
    for (; j + 3 < je; j += 4) {
        const int s0 = col[j], s1 = col[j + 1], s2 = col[j + 2], s3 = col[j + 3];
        const float w0 = w2[j], w1 = w2[j + 1], w2v = w2[j + 2], w3 = w2[j + 3];
        const float2 v0 = *(const float2*)&g2[(size_t)s0 * EMB + lane * 2];
        const float2 v1 = *(const float2*)&g2[(size_t)s1 * EMB + lane * 2];
        const float2 v2 = *(const float2*)&g2[(size_t)s2 * EMB + lane * 2];
        const float2 v3 = *(const float2*)&g2[(size_t)s3 * EMB + lane * 2];
        acc.x += w0 * v0.x + w1 * v1.x + w2v * v2.x + w3 * v3.x;
        acc.y += w0 * v0.y + w1 * v1.y + w2v * v2.y + w3 * v3.y;
        z += (w0 + w1) + (w2v + w3);
    }
    for (; j < je; j++) {
        const int s0 = col[j];
        const float w0 = w2[j];
        const float2 v0 = *(const float2*)&g2[(size_t)s0 * EMB + lane * 2];
        acc.x += w0 * v0.x; acc.y += w0 * v0.y;
        z += w0;
    }
    const float inv = 1.f / z;
    float2 o = make_float2(acc.x * inv, acc.y * inv);
    *(float2*)&out2[(size_t)w * EMB + lane * 2] = o;
}

// ---------------------------------------------------------------------------
// Global mean pool (782-block run-length form) + divide.
// ---------------------------------------------------------------------------
__global__ __launch_bounds__(128) void pool_kernel(const float* __restrict__ out2,
                                                   const float* __restrict__ b2,
                                                   const int* __restrict__ batch,
                                                   float* __restrict__ pool,
                                                   float* __restrict__ cnt, int N) {
    const int c = threadIdx.x;
    const int n0 = blockIdx.x * 64;
    const int nend = min(n0 + 64, N);
    const float bias = b2[c];
    float acc = 0.f, cacc = 0.f;
    int curg = batch[n0];
    for (int n = n0; n < nend; n++) {
        const int g = batch[n];
        if (g != curg) {
            atomicAdd(&pool[curg * EMB + c], acc);
            if (c == 0) atomicAdd(&cnt[curg], cacc);
            acc = 0.f; cacc = 0.f; curg = g;
        }
        float v = out2[(size_t)n * EMB + c] + bias;
        v = v > 0.f ? v : expm1f(v);
        acc += v;
        cacc += 1.f;
    }
    atomicAdd(&pool[curg * EMB + c], acc);
    if (c == 0) atomicAdd(&cnt[curg], cacc);
}

__global__ __launch_bounds__(256) void div_kernel(const float* __restrict__ pool,
                                                  const float* __restrict__ cnt,
                                                  float* __restrict__ out) {
    const int i = blockIdx.x * 256 + threadIdx.x;
    out[i] = pool[i] / fmaxf(cnt[i >> 7], 1.f);
}

// ---------------------------------------------------------------------------
extern "C" void kernel_launch(void* const* d_in, const int* in_sizes, int n_in,
                              void* d_out, int out_size, void* d_ws, size_t ws_size,
                              hipStream_t stream) {
    const float* x      = (const float*)d_in[0];
    const int*   ei     = (const int*)d_in[1];
    const int*   batch  = (const int*)d_in[3];
    const float* W1     = (const float*)d_in[4];
    const float* a_src1 = (const float*)d_in[5];
    const float* a_dst1 = (const float*)d_in[6];
    const float* b1     = (const float*)d_in[7];
    const float* W2     = (const float*)d_in[8];
    const float* a_src2 = (const float*)d_in[9];
    const float* a_dst2 = (const float*)d_in[10];
    const float* b2     = (const float*)d_in[11];
    float* out = (float*)d_out;

    const int N = N_NODES, E = N_EDGES;

    size_t cur_off = 0;
    auto carve = [&](size_t bytes) {
        size_t o = cur_off;
        cur_off = (cur_off + bytes + 255) & ~(size_t)255;
        return (char*)d_ws + o;
    };
    // zero-init region: deg + pool + cnt
    int* deg     = (int*)carve((size_t)N * 4);
    float* pool  = (float*)carve((size_t)N_GRAPHS * EMB * 4);
    float* cnt   = (float*)carve((size_t)N_GRAPHS * 4);
    const size_t zero_bytes = cur_off;
    int* curp    = (int*)carve((size_t)N * 4);
    int* partial = (int*)carve((size_t)SCAN_BLOCKS * 4);
    __bf16* B1h  = (__bf16*)carve((size_t)HEADS * W1_FRAG * 2);
    __bf16* B1l  = (__bf16*)carve((size_t)HEADS * W1_FRAG * 2);
    __bf16* B2h  = (__bf16*)carve((size_t)F1 * EMB * 2);
    __bf16* B2l  = (__bf16*)carve((size_t)F1 * EMB * 2);
    int* off     = (int*)carve((size_t)(N + 1) * 4);
    int* col     = (int*)carve((size_t)E * 4);
    int* rowd    = (int*)carve((size_t)E * 4);
    float4* w4   = (float4*)carve((size_t)E * 16);
    float* w2    = (float*)carve((size_t)E * 4);
    float* aggx  = (float*)carve((size_t)N * HEADS * IN_DIM * 4);
    float* g2    = (float*)carve((size_t)N * EMB * 4);
    float* out2  = (float*)carve((size_t)N * EMB * 4);
    float* as1   = (float*)carve((size_t)N * HEADS * 4);
    float* ad1   = (float*)carve((size_t)N * HEADS * 4);
    float* as2   = (float*)carve((size_t)N * 4);
    float* ad2   = (float*)carve((size_t)N * 4);

    hipMemsetAsync(d_ws, 0, zero_bytes, stream);

    prep_kernel<<<DEG_BLOCKS + 32, 256, 0, stream>>>(ei, deg, W1, B1h, B1l, W2, B2h, B2l);

    scanA_kernel<<<SCAN_BLOCKS, 256, 0, stream>>>(deg, off, partial, N);
    scanB_kernel<<<1, 256, 0, stream>>>(partial, &off[N]);
    scanC_kernel<<<SCAN_BLOCKS, 256, 0, stream>>>(off, partial, curp, N);

    // gemm1 (x -> as1/ad1), then scatter fused with edge-weight computation
    gemm1_kernel<<<(N + 63) / 64, 256, 0, stream>>>(x, B1h, B1l, a_src1, a_dst1,
                                                    as1, ad1, N);
    scatter_w1_kernel<<<DEG_BLOCKS, 256, 0, stream>>>(ei, off, curp, col, rowd,
                                                      as1, ad1, w4, E);

    agg1x_kernel<<<(N + 3) / 4, 256, 0, stream>>>(off, col, w4, x, as1, ad1, aggx, N);

    // fused: (aggx @ W1 -> ELU -> @ W2) + alpha2, half-K LDS staging
    gemm12_kernel<<<(N + 31) / 32, 128, 0, stream>>>(aggx, B1h, B1l, b1, B2h, B2l,
                                                     a_src2, a_dst2, g2, as2, ad2, N);

    w2_kernel<<<DEG_BLOCKS, 256, 0, stream>>>(col, rowd, as2, ad2, w2, E);
    agg2_kernel<<<(N + 3) / 4, 256, 0, stream>>>(off, col, w2, g2, as2, ad2, out2, N);

    pool_kernel<<<(N + 63) / 64, 128, 0, stream>>>(out2, b2, batch, pool, cnt, N);
    div_kernel<<<(N_GRAPHS * EMB) / 256, 256, 0, stream>>>(pool, cnt, out);
}

// Round 11
// 429.056 us; speedup vs baseline: 1.1322x; 1.1322x over previous
//
#include <hip/hip_runtime.h>
#include <hip/hip_bf16.h>
#include <cstddef>

// Problem constants (fixed-shape problem)
constexpr int N_NODES = 50000;
constexpr int N_EDGES = 800000;
constexpr int IN_DIM  = 128;
constexpr int HID     = 64;
constexpr int HEADS   = 4;
constexpr int F1      = HEADS * HID;  // 256
constexpr int EMB     = 128;
constexpr int N_GRAPHS = 64;

constexpr int DEG_BLOCKS   = (N_EDGES + 255) / 256;  // 3125
constexpr int SCAN_BLOCKS  = (N_NODES + 255) / 256;  // 196
// per-head W1 fragment size (NT=4, KK=4): 4*4*64*8 bf16 elements
constexpr int W1_FRAG = 4 * 4 * 64 * 8;              // 8192
// Fused-kernel LDS row stride (f32): 256 cols + 4 pad (132*4=528 B, 16B-aligned;
// 132 mod 32 = 4 keeps b128 reads ~2-way bank-aliased = free, m136).
constexpr int LDP = 260 + 4;  // not used; see LDP16 below
// 16-row tile stride: 256 cols + 4 pad? tile is 16 x 256 -> stride 260? No:
// phase-1 writes cols 0..255 per row; stride must cover 256 cols.
constexpr int LDP16 = 260;    // 260 mod 32 = 4 -> 2-way alias; 260*4=1040 B (16B-aligned)

typedef __bf16 bf16x8 __attribute__((ext_vector_type(8)));
typedef float  f32x4  __attribute__((ext_vector_type(4)));

__device__ __forceinline__ float lrelu(float x) { return x > 0.f ? x : 0.2f * x; }
__device__ __forceinline__ float eluf(float x)  { return x > 0.f ? x : expm1f(x); }

// ---------------------------------------------------------------------------
// Pack a [K x 16*NT] submatrix of B (leading dim ld, origin col0) into
// per-lane MFMA B-fragments, split hi/lo bf16.
// ---------------------------------------------------------------------------
__device__ __forceinline__ void pack_frag(const float* __restrict__ B,
                                          __bf16* __restrict__ hi,
                                          __bf16* __restrict__ lo,
                                          int pblk, int NT, int KK, int ld, int col0) {
    const int gid = pblk * 256 + threadIdx.x;
    if (gid >= NT * KK * 64) return;
    const int lane = gid & 63;
    const int rem  = gid >> 6;
    const int kk   = rem % KK;
    const int t    = rem / KK;
    const int n    = col0 + t * 16 + (lane & 15);
    const int k0   = kk * 32 + (lane >> 4) * 8;
#pragma unroll
    for (int j = 0; j < 8; j++) {
        const float v = B[(size_t)(k0 + j) * ld + n];
        const __bf16 h = (__bf16)v;
        hi[(size_t)gid * 8 + j] = h;
        lo[(size_t)gid * 8 + j] = (__bf16)(v - (float)h);
    }
}

// ---------------------------------------------------------------------------
// prep: [deg histogram | pack W1 per-head | pack W2] by block range.
// ---------------------------------------------------------------------------
__global__ __launch_bounds__(256) void prep_kernel(const int* __restrict__ ei,
                                                   int* __restrict__ deg,
                                                   const float* __restrict__ W1,
                                                   __bf16* __restrict__ B1h,
                                                   __bf16* __restrict__ B1l,
                                                   const float* __restrict__ W2,
                                                   __bf16* __restrict__ B2h,
                                                   __bf16* __restrict__ B2l) {
    const int b = blockIdx.x;
    if (b < DEG_BLOCKS) {
        const int e = b * 256 + threadIdx.x;
        if (e < N_EDGES) atomicAdd(&deg[ei[N_EDGES + e]], 1);
        return;
    }
    const int pb = b - DEG_BLOCKS;
    if (pb < 16) {
        const int head = pb >> 2;
        pack_frag(W1, B1h + head * W1_FRAG, B1l + head * W1_FRAG,
                  pb & 3, 4, 4, F1, head * HID);
    } else {
        pack_frag(W2, B2h, B2l, pb - 16, 8, 8, EMB, 0);
    }
}

// ---------------------------------------------------------------------------
// 3-phase parallel scan (deg -> off); phase C also zeroes cur.
// ---------------------------------------------------------------------------
__global__ __launch_bounds__(256) void scanA_kernel(const int* __restrict__ deg,
                                                    int* __restrict__ off,
                                                    int* __restrict__ partial, int N) {
    __shared__ int sm[256];
    const int t = threadIdx.x;
    const int i = blockIdx.x * 256 + t;
    const int v = (i < N) ? deg[i] : 0;
    sm[t] = v;
    __syncthreads();
    int val = v;
#pragma unroll
    for (int o = 1; o < 256; o <<= 1) {
        const int add = (t >= o) ? sm[t - o] : 0;
        __syncthreads();
        val += add;
        sm[t] = val;
        __syncthreads();
    }
    if (i < N) off[i] = val - v;
    if (t == 255) partial[blockIdx.x] = val;
}

__global__ __launch_bounds__(256) void scanB_kernel(int* __restrict__ partial,
                                                    int* __restrict__ off_last) {
    __shared__ int sm[256];
    const int t = threadIdx.x;
    const int v = (t < SCAN_BLOCKS) ? partial[t] : 0;
    sm[t] = v;
    __syncthreads();
    int val = v;
#pragma unroll
    for (int o = 1; o < 256; o <<= 1) {
        const int add = (t >= o) ? sm[t - o] : 0;
        __syncthreads();
        val += add;
        sm[t] = val;
        __syncthreads();
    }
    if (t < SCAN_BLOCKS) partial[t] = val - v;
    if (t == SCAN_BLOCKS - 1) *off_last = val;
}

__global__ __launch_bounds__(256) void scanC_kernel(int* __restrict__ off,
                                                    const int* __restrict__ partial,
                                                    int* __restrict__ cur, int N) {
    const int i = blockIdx.x * 256 + threadIdx.x;
    if (i < N) {
        off[i] += partial[blockIdx.x];
        cur[i] = 0;
    }
}

// ---------------------------------------------------------------------------
// gemm1: as1/ad1 = alpha-logits of (x @ W1). No C store.
// ---------------------------------------------------------------------------
__global__ __launch_bounds__(256) void gemm1_kernel(
        const float* __restrict__ A, const __bf16* __restrict__ Bh,
        const __bf16* __restrict__ Bl, const float* __restrict__ avs,
        const float* __restrict__ avd, float* __restrict__ as_out,
        float* __restrict__ ad_out, int M) {
    constexpr int NT = F1 / 16, KK = IN_DIM / 32, NH = HEADS;
    constexpr int Ncols = NT * 16;
    constexpr int K = KK * 32;
    const int tid  = threadIdx.x;
    const int wave = tid >> 6, lane = tid & 63;
    const int quad = lane >> 4, l16 = lane & 15;
    const int rowA = min((int)blockIdx.x * 64 + wave * 16 + l16, M - 1);

    f32x4 acc[NT];
#pragma unroll
    for (int t = 0; t < NT; t++) acc[t] = (f32x4){0.f, 0.f, 0.f, 0.f};

    for (int kk = 0; kk < KK; kk++) {
        const int k0 = kk * 32 + quad * 8;
        float a8[8];
        *(float4*)&a8[0] = *(const float4*)&A[(size_t)rowA * K + k0];
        *(float4*)&a8[4] = *(const float4*)&A[(size_t)rowA * K + k0 + 4];
        bf16x8 ah, al;
#pragma unroll
        for (int j = 0; j < 8; j++) {
            const __bf16 h = (__bf16)a8[j];
            ah[j] = h;
            al[j] = (__bf16)(a8[j] - (float)h);
        }
#pragma unroll
        for (int t = 0; t < NT; t++) {
            const size_t bi = ((size_t)(t * KK + kk) * 64 + lane) * 8;
            bf16x8 bhv = *(const bf16x8*)&Bh[bi];
            bf16x8 blv = *(const bf16x8*)&Bl[bi];
            acc[t] = __builtin_amdgcn_mfma_f32_16x16x32_bf16(ah, bhv, acc[t], 0, 0, 0);
            acc[t] = __builtin_amdgcn_mfma_f32_16x16x32_bf16(al, bhv, acc[t], 0, 0, 0);
            acc[t] = __builtin_amdgcn_mfma_f32_16x16x32_bf16(ah, blv, acc[t], 0, 0, 0);
        }
    }

    const int rowS = blockIdx.x * 64 + wave * 16 + quad * 4;
#pragma unroll
    for (int r = 0; r < 4; r++) {
        float ps[NH], pd[NH];
#pragma unroll
        for (int h = 0; h < NH; h++) { ps[h] = 0.f; pd[h] = 0.f; }
#pragma unroll
        for (int t = 0; t < NT; t++) {
            const int h = (t * 16) / (Ncols / NH);
            const int col = t * 16 + l16;
            ps[h] += acc[t][r] * avs[col];
            pd[h] += acc[t][r] * avd[col];
        }
#pragma unroll
        for (int o = 1; o < 16; o <<= 1) {
#pragma unroll
            for (int h = 0; h < NH; h++) {
                ps[h] += __shfl_xor(ps[h], o);
                pd[h] += __shfl_xor(pd[h], o);
            }
        }
        const int rr = rowS + r;
        if (l16 == 0 && rr < M) {
#pragma unroll
            for (int h = 0; h < NH; h++) {
                as_out[rr * NH + h] = ps[h];
                ad_out[rr * NH + h] = pd[h];
            }
        }
    }
}

// CSR scatter fused with layer-1 edge-weight computation (as1/ad1 ready).
__global__ __launch_bounds__(256) void scatter_w1_kernel(
        const int* __restrict__ ei, const int* __restrict__ off,
        int* __restrict__ cur, int* __restrict__ col, int* __restrict__ row,
        const float* __restrict__ as1, const float* __restrict__ ad1,
        float4* __restrict__ w4, int E) {
    const int e = blockIdx.x * 256 + threadIdx.x;
    if (e >= E) return;
    const int s = ei[e], d = ei[E + e];
    const int pos = atomicAdd(&cur[d], 1);
    const int slot = off[d] + pos;
    col[slot] = s;
    row[slot] = d;
    const float4 a = *(const float4*)&as1[s * HEADS];
    const float4 b = *(const float4*)&ad1[d * HEADS];
    float4 o;
    o.x = expf(lrelu(a.x + b.x));
    o.y = expf(lrelu(a.y + b.y));
    o.z = expf(lrelu(a.z + b.z));
    o.w = expf(lrelu(a.w + b.w));
    w4[slot] = o;
}

// Layer-2 edge weights (one exp per edge instead of 64).
__global__ __launch_bounds__(256) void w2_kernel(const int* __restrict__ col,
                                                 const int* __restrict__ row,
                                                 const float* __restrict__ as2,
                                                 const float* __restrict__ ad2,
                                                 float* __restrict__ w2, int E) {
    const int i = blockIdx.x * 256 + threadIdx.x;
    if (i >= E) return;
    w2[i] = expf(lrelu(as2[col[i]] + ad2[row[i]]));
}

// ---------------------------------------------------------------------------
// Layer-1 x-aggregation: one wave per dst node, scalarized uniform accesses,
// 4-edge unroll. aggx[node][head][:] = (sum_e w_e x[src_e]) / z_h.
// ---------------------------------------------------------------------------
__global__ __launch_bounds__(256) void agg1x_kernel(const int* __restrict__ off,
                                                    const int* __restrict__ col,
                                                    const float4* __restrict__ w4,
                                                    const float* __restrict__ x,
                                                    const float* __restrict__ as1,
                                                    const float* __restrict__ ad1,
                                                    float* __restrict__ aggx, int N) {
    const int w = __builtin_amdgcn_readfirstlane((blockIdx.x * 256 + threadIdx.x) >> 6);
    const int lane = threadIdx.x & 63;
    if (w >= N) return;

    float2 acc[HEADS];
    float z[HEADS];
#pragma unroll
    for (int h = 0; h < HEADS; h++) { acc[h] = make_float2(0.f, 0.f); z[h] = 0.f; }

    {   // self-loop
        const float4 asv = *(const float4*)&as1[w * HEADS];
        const float4 adv = *(const float4*)&ad1[w * HEADS];
        const float2 xv = *(const float2*)&x[(size_t)w * IN_DIM + lane * 2];
        float ws[HEADS] = {expf(lrelu(asv.x + adv.x)), expf(lrelu(asv.y + adv.y)),
                           expf(lrelu(asv.z + adv.z)), expf(lrelu(asv.w + adv.w))};
#pragma unroll
        for (int h = 0; h < HEADS; h++) {
            acc[h].x += ws[h] * xv.x; acc[h].y += ws[h] * xv.y; z[h] += ws[h];
        }
    }
    const int jb = off[w], je = off[w + 1];
    int j = jb;
    for (; j + 3 < je; j += 4) {
        const int s0 = col[j], s1 = col[j + 1], s2 = col[j + 2], s3 = col[j + 3];
        const float4 w0 = w4[j], w1 = w4[j + 1], w2 = w4[j + 2], w3 = w4[j + 3];
        const float2 v0 = *(const float2*)&x[(size_t)s0 * IN_DIM + lane * 2];
        const float2 v1 = *(const float2*)&x[(size_t)s1 * IN_DIM + lane * 2];
        const float2 v2 = *(const float2*)&x[(size_t)s2 * IN_DIM + lane * 2];
        const float2 v3 = *(const float2*)&x[(size_t)s3 * IN_DIM + lane * 2];
        acc[0].x += w0.x * v0.x + w1.x * v1.x + w2.x * v2.x + w3.x * v3.x;
        acc[0].y += w0.x * v0.y + w1.x * v1.y + w2.x * v2.y + w3.x * v3.y;
        acc[1].x += w0.y * v0.x + w1.y * v1.x + w2.y * v2.x + w3.y * v3.x;
        acc[1].y += w0.y * v0.y + w1.y * v1.y + w2.y * v2.y + w3.y * v3.y;
        acc[2].x += w0.z * v0.x + w1.z * v1.x + w2.z * v2.x + w3.z * v3.x;
        acc[2].y += w0.z * v0.y + w1.z * v1.y + w2.z * v2.y + w3.z * v3.y;
        acc[3].x += w0.w * v0.x + w1.w * v1.x + w2.w * v2.x + w3.w * v3.x;
        acc[3].y += w0.w * v0.y + w1.w * v1.y + w2.w * v2.y + w3.w * v3.y;
        z[0] += (w0.x + w1.x) + (w2.x + w3.x);
        z[1] += (w0.y + w1.y) + (w2.y + w3.y);
        z[2] += (w0.z + w1.z) + (w2.z + w3.z);
        z[3] += (w0.w + w1.w) + (w2.w + w3.w);
    }
    for (; j < je; j++) {
        const int s0 = col[j];
        const float4 w0 = w4[j];
        const float2 v0 = *(const float2*)&x[(size_t)s0 * IN_DIM + lane * 2];
        acc[0].x += w0.x * v0.x; acc[0].y += w0.x * v0.y; z[0] += w0.x;
        acc[1].x += w0.y * v0.x; acc[1].y += w0.y * v0.y; z[1] += w0.y;
        acc[2].x += w0.z * v0.x; acc[2].y += w0.z * v0.y; z[2] += w0.z;
        acc[3].x += w0.w * v0.x; acc[3].y += w0.w * v0.y; z[3] += w0.w;
    }
#pragma unroll
    for (int h = 0; h < HEADS; h++) {
        const float inv = 1.f / z[h];
        float2 o = make_float2(acc[h].x * inv, acc[h].y * inv);
        *(float2*)&aggx[((size_t)w * HEADS + h) * IN_DIM + lane * 2] = o;
    }
}

// ---------------------------------------------------------------------------
// FUSED layer-1-reconstruct + layer-2 GEMM, 16 rows/block, 4 waves:
//   phase 1: wave w computes head w (16 rows x 64 cols), ELU(+b1) -> LDS
//   phase 2: wave w computes output cols [32w, 32w+32) from the shared tile
// R10's 32-row/2-wave version supplied only ~12 waves/CU (grid-limited,
// occupancy 19%, all pipes idle). This shape gives 3125 blocks x 4 waves =
// ~49 waves/CU of demand at 9 KB LDS. N = 3125*16 exactly (no tail).
// ---------------------------------------------------------------------------
__global__ __launch_bounds__(256) void gemm12_kernel(
        const float* __restrict__ aggx,
        const __bf16* __restrict__ B1h, const __bf16* __restrict__ B1l,
        const float* __restrict__ b1,
        const __bf16* __restrict__ B2h, const __bf16* __restrict__ B2l,
        const float* __restrict__ avs, const float* __restrict__ avd,
        float* __restrict__ g2, float* __restrict__ as_out,
        float* __restrict__ ad_out, int M) {
    __shared__ float sm[16 * LDP16];
    __shared__ float pps[4][16], pdd[4][16];
    const int tid  = threadIdx.x;
    const int wave = tid >> 6, lane = tid & 63;
    const int quad = lane >> 4, l16 = lane & 15;
    const int row0 = blockIdx.x * 16;
    const int rowA = min(row0 + l16, M - 1);

    // ---- phase 1: this wave's head = `wave` ----
    {
        f32x4 acc1[4];
#pragma unroll
        for (int t = 0; t < 4; t++) acc1[t] = (f32x4){0.f, 0.f, 0.f, 0.f};
        const float* Arow = aggx + ((size_t)rowA * HEADS + wave) * IN_DIM;
#pragma unroll
        for (int kk = 0; kk < 4; kk++) {
            const int k0 = kk * 32 + quad * 8;
            float a8[8];
            *(float4*)&a8[0] = *(const float4*)&Arow[k0];
            *(float4*)&a8[4] = *(const float4*)&Arow[k0 + 4];
            bf16x8 ah, al;
#pragma unroll
            for (int j = 0; j < 8; j++) {
                const __bf16 hh = (__bf16)a8[j];
                ah[j] = hh;
                al[j] = (__bf16)(a8[j] - (float)hh);
            }
#pragma unroll
            for (int t = 0; t < 4; t++) {
                const size_t bi = (size_t)wave * W1_FRAG +
                                  ((size_t)(t * 4 + kk) * 64 + lane) * 8;
                bf16x8 bhv = *(const bf16x8*)&B1h[bi];
                bf16x8 blv = *(const bf16x8*)&B1l[bi];
                acc1[t] = __builtin_amdgcn_mfma_f32_16x16x32_bf16(ah, bhv, acc1[t], 0, 0, 0);
                acc1[t] = __builtin_amdgcn_mfma_f32_16x16x32_bf16(al, bhv, acc1[t], 0, 0, 0);
                acc1[t] = __builtin_amdgcn_mfma_f32_16x16x32_bf16(ah, blv, acc1[t], 0, 0, 0);
            }
        }
        // ELU(+b1) -> LDS: row = quad*4 + r, col = wave*64 + t*16 + l16
#pragma unroll
        for (int t = 0; t < 4; t++) {
            const int c = wave * 64 + t * 16 + l16;
            const float bb = b1[c];
#pragma unroll
            for (int r = 0; r < 4; r++) {
                sm[(quad * 4 + r) * LDP16 + c] = eluf(acc1[t][r] + bb);
            }
        }
    }
    __syncthreads();

    // ---- phase 2: this wave's output cols = tiles {2*wave, 2*wave+1} ----
    f32x4 acc2[2];
#pragma unroll
    for (int t = 0; t < 2; t++) acc2[t] = (f32x4){0.f, 0.f, 0.f, 0.f};
    const int arow = l16 * LDP16;
#pragma unroll
    for (int kk = 0; kk < 8; kk++) {
        const int k0 = kk * 32 + quad * 8;
        float a8[8];
        *(float4*)&a8[0] = *(const float4*)&sm[arow + k0];
        *(float4*)&a8[4] = *(const float4*)&sm[arow + k0 + 4];
        bf16x8 ah, al;
#pragma unroll
        for (int j = 0; j < 8; j++) {
            const __bf16 hh = (__bf16)a8[j];
            ah[j] = hh;
            al[j] = (__bf16)(a8[j] - (float)hh);
        }
#pragma unroll
        for (int tt = 0; tt < 2; tt++) {
            const int t = wave * 2 + tt;
            const size_t bi = ((size_t)(t * 8 + kk) * 64 + lane) * 8;
            bf16x8 bhv = *(const bf16x8*)&B2h[bi];
            bf16x8 blv = *(const bf16x8*)&B2l[bi];
            acc2[tt] = __builtin_amdgcn_mfma_f32_16x16x32_bf16(ah, bhv, acc2[tt], 0, 0, 0);
            acc2[tt] = __builtin_amdgcn_mfma_f32_16x16x32_bf16(al, bhv, acc2[tt], 0, 0, 0);
            acc2[tt] = __builtin_amdgcn_mfma_f32_16x16x32_bf16(ah, blv, acc2[tt], 0, 0, 0);
        }
    }

    // store g2 + alpha2 logit partials
    const int rowS = row0 + quad * 4;
#pragma unroll
    for (int tt = 0; tt < 2; tt++) {
        const int t = wave * 2 + tt;
#pragma unroll
        for (int r = 0; r < 4; r++) {
            const int rr = rowS + r;
            if (rr < M) g2[(size_t)rr * EMB + t * 16 + l16] = acc2[tt][r];
        }
    }
#pragma unroll
    for (int r = 0; r < 4; r++) {
        float ps = 0.f, pd = 0.f;
#pragma unroll
        for (int tt = 0; tt < 2; tt++) {
            const int c = (wave * 2 + tt) * 16 + l16;
            ps += acc2[tt][r] * avs[c];
            pd += acc2[tt][r] * avd[c];
        }
#pragma unroll
        for (int o = 1; o < 16; o <<= 1) {
            ps += __shfl_xor(ps, o);
            pd += __shfl_xor(pd, o);
        }
        if (l16 == 0) {
            pps[wave][quad * 4 + r] = ps;
            pdd[wave][quad * 4 + r] = pd;
        }
    }
    __syncthreads();
    if (tid < 16) {
        const int rr = row0 + tid;
        if (rr < M) {
            as_out[rr] = pps[0][tid] + pps[1][tid] + pps[2][tid] + pps[3][tid];
            ad_out[rr] = pdd[0][tid] + pdd[1][tid] + pdd[2][tid] + pdd[3][tid];
        }
    }
}

// ---------------------------------------------------------------------------
// Layer-2 aggregation: one wave per dst node, precomputed scalar weights.
// ---------------------------------------------------------------------------
__global__ __launch_bounds__(256) void agg2_kernel(const int* __restrict__ off,
                                                   const int* __restrict__ col,
                                                   const float* __restrict__ w2,
                                                   const float* __restrict__ g2,
                                                   const float* __restrict__ as2,
                                                   const float* __restrict__ ad2,
                                                   float* __restrict__ out2, int N) {
    const int w = __builtin_amdgcn_readfirstlane((blockIdx.x * 256 + threadIdx.x) >> 6);
    const int lane = threadIdx.x & 63;
    if (w >= N) return;

    float2 acc = make_float2(0.f, 0.f);
    float z = 0.f;
    {   // self-loop
        const float wt = expf(lrelu(as2[w] + ad2[w]));
        float2 hv = *(const float2*)&g2[(size_t)w * EMB + lane * 2];
        acc.x += wt * hv.x; acc.y += wt * hv.y;
        z += wt;
    }
    const int jb = off[w], je = off[w + 1];
    int j = jb;
    for (; j + 3 < je; j += 4) {
        const int s0 = col[j], s1 = col[j + 1], s2 = col[j + 2], s3 = col[j + 3];
        const float w0 = w2[j], w1 = w2[j + 1], w2v = w2[j + 2], w3 = w2[j + 3];
        const float2 v0 = *(const float2*)&g2[(size_t)s0 * EMB + lane * 2];
        const float2 v1 = *(const float2*)&g2[(size_t)s1 * EMB + lane * 2];
        const float2 v2 = *(const float2*)&g2[(size_t)s2 * EMB + lane * 2];
        const float2 v3 = *(const float2*)&g2[(size_t)s3 * EMB + lane * 2];
        acc.x += w0 * v0.x + w1 * v1.x + w2v * v2.x + w3 * v3.x;
        acc.y += w0 * v0.y + w1 * v1.y + w2v * v2.y + w3 * v3.y;
        z += (w0 + w1) + (w2v + w3);
    }
    for (; j < je; j++) {
        const int s0 = col[j];
        const float w0 = w2[j];
        const float2 v0 = *(const float2*)&g2[(size_t)s0 * EMB + lane * 2];
        acc.x += w0 * v0.x; acc.y += w0 * v0.y;
        z += w0;
    }
    const float inv = 1.f / z;
    float2 o = make_float2(acc.x * inv, acc.y * inv);
    *(float2*)&out2[(size_t)w * EMB + lane * 2] = o;
}

// ---------------------------------------------------------------------------
// Global mean pool (782-block run-length form) + divide.
// ---------------------------------------------------------------------------
__global__ __launch_bounds__(128) void pool_kernel(const float* __restrict__ out2,
                                                   const float* __restrict__ b2,
                                                   const int* __restrict__ batch,
                                                   float* __restrict__ pool,
                                                   float* __restrict__ cnt, int N) {
    const int c = threadIdx.x;
    const int n0 = blockIdx.x * 64;
    const int nend = min(n0 + 64, N);
    const float bias = b2[c];
    float acc = 0.f, cacc = 0.f;
    int curg = batch[n0];
    for (int n = n0; n < nend; n++) {
        const int g = batch[n];
        if (g != curg) {
            atomicAdd(&pool[curg * EMB + c], acc);
            if (c == 0) atomicAdd(&cnt[curg], cacc);
            acc = 0.f; cacc = 0.f; curg = g;
        }
        float v = out2[(size_t)n * EMB + c] + bias;
        v = v > 0.f ? v : expm1f(v);
        acc += v;
        cacc += 1.f;
    }
    atomicAdd(&pool[curg * EMB + c], acc);
    if (c == 0) atomicAdd(&cnt[curg], cacc);
}

__global__ __launch_bounds__(256) void div_kernel(const float* __restrict__ pool,
                                                  const float* __restrict__ cnt,
                                                  float* __restrict__ out) {
    const int i = blockIdx.x * 256 + threadIdx.x;
    out[i] = pool[i] / fmaxf(cnt[i >> 7], 1.f);
}

// ---------------------------------------------------------------------------
extern "C" void kernel_launch(void* const* d_in, const int* in_sizes, int n_in,
                              void* d_out, int out_size, void* d_ws, size_t ws_size,
                              hipStream_t stream) {
    const float* x      = (const float*)d_in[0];
    const int*   ei     = (const int*)d_in[1];
    const int*   batch  = (const int*)d_in[3];
    const float* W1     = (const float*)d_in[4];
    const float* a_src1 = (const float*)d_in[5];
    const float* a_dst1 = (const float*)d_in[6];
    const float* b1     = (const float*)d_in[7];
    const float* W2     = (const float*)d_in[8];
    const float* a_src2 = (const float*)d_in[9];
    const float* a_dst2 = (const float*)d_in[10];
    const float* b2     = (const float*)d_in[11];
    float* out = (float*)d_out;

    const int N = N_NODES, E = N_EDGES;

    size_t cur_off = 0;
    auto carve = [&](size_t bytes) {
        size_t o = cur_off;
        cur_off = (cur_off + bytes + 255) & ~(size_t)255;
        return (char*)d_ws + o;
    };
    // zero-init region: deg + pool + cnt
    int* deg     = (int*)carve((size_t)N * 4);
    float* pool  = (float*)carve((size_t)N_GRAPHS * EMB * 4);
    float* cnt   = (float*)carve((size_t)N_GRAPHS * 4);
    const size_t zero_bytes = cur_off;
    int* curp    = (int*)carve((size_t)N * 4);
    int* partial = (int*)carve((size_t)SCAN_BLOCKS * 4);
    __bf16* B1h  = (__bf16*)carve((size_t)HEADS * W1_FRAG * 2);
    __bf16* B1l  = (__bf16*)carve((size_t)HEADS * W1_FRAG * 2);
    __bf16* B2h  = (__bf16*)carve((size_t)F1 * EMB * 2);
    __bf16* B2l  = (__bf16*)carve((size_t)F1 * EMB * 2);
    int* off     = (int*)carve((size_t)(N + 1) * 4);
    int* col     = (int*)carve((size_t)E * 4);
    int* rowd    = (int*)carve((size_t)E * 4);
    float4* w4   = (float4*)carve((size_t)E * 16);
    float* w2    = (float*)carve((size_t)E * 4);
    float* aggx  = (float*)carve((size_t)N * HEADS * IN_DIM * 4);
    float* g2    = (float*)carve((size_t)N * EMB * 4);
    float* out2  = (float*)carve((size_t)N * EMB * 4);
    float* as1   = (float*)carve((size_t)N * HEADS * 4);
    float* ad1   = (float*)carve((size_t)N * HEADS * 4);
    float* as2   = (float*)carve((size_t)N * 4);
    float* ad2   = (float*)carve((size_t)N * 4);

    hipMemsetAsync(d_ws, 0, zero_bytes, stream);

    prep_kernel<<<DEG_BLOCKS + 32, 256, 0, stream>>>(ei, deg, W1, B1h, B1l, W2, B2h, B2l);

    scanA_kernel<<<SCAN_BLOCKS, 256, 0, stream>>>(deg, off, partial, N);
    scanB_kernel<<<1, 256, 0, stream>>>(partial, &off[N]);
    scanC_kernel<<<SCAN_BLOCKS, 256, 0, stream>>>(off, partial, curp, N);

    // gemm1 (x -> as1/ad1), then scatter fused with edge-weight computation
    gemm1_kernel<<<(N + 63) / 64, 256, 0, stream>>>(x, B1h, B1l, a_src1, a_dst1,
                                                    as1, ad1, N);
    scatter_w1_kernel<<<DEG_BLOCKS, 256, 0, stream>>>(ei, off, curp, col, rowd,
                                                      as1, ad1, w4, E);

    agg1x_kernel<<<(N + 3) / 4, 256, 0, stream>>>(off, col, w4, x, as1, ad1, aggx, N);

    // fused: (aggx @ W1 -> ELU -> @ W2) + alpha2; 16 rows/block, 4 waves
    gemm12_kernel<<<(N + 15) / 16, 256, 0, stream>>>(aggx, B1h, B1l, b1, B2h, B2l,
                                                     a_src2, a_dst2, g2, as2, ad2, N);

    w2_kernel<<<DEG_BLOCKS, 256, 0, stream>>>(col, rowd, as2, ad2, w2, E);
    agg2_kernel<<<(N + 3) / 4, 256, 0, stream>>>(off, col, w2, g2, as2, ad2, out2, N);

    pool_kernel<<<(N + 63) / 64, 128, 0, stream>>>(out2, b2, batch, pool, cnt, N);
    div_kernel<<<(N_GRAPHS * EMB) / 256, 256, 0, stream>>>(pool, cnt, out);
}

// Round 12
// 380.406 us; speedup vs baseline: 1.2770x; 1.1279x over previous
//
#include <hip/hip_runtime.h>
#include <hip/hip_bf16.h>
#include <cstddef>

// Problem constants (fixed-shape problem)
constexpr int N_NODES = 50000;
constexpr int N_EDGES = 800000;
constexpr int IN_DIM  = 128;
constexpr int HID     = 64;
constexpr int HEADS   = 4;
constexpr int F1      = HEADS * HID;  // 256
constexpr int EMB     = 128;
constexpr int N_GRAPHS = 64;

constexpr int DEG_BLOCKS   = (N_EDGES + 255) / 256;          // 3125
constexpr int SCAN_BLOCKS  = (N_NODES + 255) / 256;          // 196
constexpr int XCONV_BLOCKS = (N_NODES * IN_DIM / 4) / 256;   // 6250 (exact)
// per-head W1 fragment size (NT=4, KK=4): 4*4*64*8 bf16 elements
constexpr int W1_FRAG = 4 * 4 * 64 * 8;                      // 8192
// gemm12 16-row LDS tile stride: 260 mod 32 = 4 -> 2-way alias (free, m136)
constexpr int LDP16 = 260;

typedef __bf16 bf16x8 __attribute__((ext_vector_type(8)));
typedef __bf16 bf16x2 __attribute__((ext_vector_type(2)));
typedef float  f32x4  __attribute__((ext_vector_type(4)));

__device__ __forceinline__ float lrelu(float x) { return x > 0.f ? x : 0.2f * x; }
__device__ __forceinline__ float eluf(float x)  { return x > 0.f ? x : expm1f(x); }

// ---------------------------------------------------------------------------
// Pack a [K x 16*NT] submatrix of B (leading dim ld, origin col0) into
// per-lane MFMA B-fragments, split hi/lo bf16.
// ---------------------------------------------------------------------------
__device__ __forceinline__ void pack_frag(const float* __restrict__ B,
                                          __bf16* __restrict__ hi,
                                          __bf16* __restrict__ lo,
                                          int pblk, int NT, int KK, int ld, int col0) {
    const int gid = pblk * 256 + threadIdx.x;
    if (gid >= NT * KK * 64) return;
    const int lane = gid & 63;
    const int rem  = gid >> 6;
    const int kk   = rem % KK;
    const int t    = rem / KK;
    const int n    = col0 + t * 16 + (lane & 15);
    const int k0   = kk * 32 + (lane >> 4) * 8;
#pragma unroll
    for (int j = 0; j < 8; j++) {
        const float v = B[(size_t)(k0 + j) * ld + n];
        const __bf16 h = (__bf16)v;
        hi[(size_t)gid * 8 + j] = h;
        lo[(size_t)gid * 8 + j] = (__bf16)(v - (float)h);
    }
}

// ---------------------------------------------------------------------------
// prep: [deg histogram | pack W1 | pack W2 | x -> bf16 copy] by block range.
// The bf16 x-copy halves the agg1x gather bytes (weights/logits stay f32).
// ---------------------------------------------------------------------------
__global__ __launch_bounds__(256) void prep_kernel(const int* __restrict__ ei,
                                                   int* __restrict__ deg,
                                                   const float* __restrict__ W1,
                                                   __bf16* __restrict__ B1h,
                                                   __bf16* __restrict__ B1l,
                                                   const float* __restrict__ W2,
                                                   __bf16* __restrict__ B2h,
                                                   __bf16* __restrict__ B2l,
                                                   const float* __restrict__ x,
                                                   __bf16* __restrict__ xb) {
    const int b = blockIdx.x;
    if (b < DEG_BLOCKS) {
        const int e = b * 256 + threadIdx.x;
        if (e < N_EDGES) atomicAdd(&deg[ei[N_EDGES + e]], 1);
        return;
    }
    const int pb = b - DEG_BLOCKS;
    if (pb < 16) {
        const int head = pb >> 2;
        pack_frag(W1, B1h + head * W1_FRAG, B1l + head * W1_FRAG,
                  pb & 3, 4, 4, F1, head * HID);
        return;
    }
    if (pb < 32) {
        pack_frag(W2, B2h, B2l, pb - 16, 8, 8, EMB, 0);
        return;
    }
    // x -> bf16 (float4 in, 4x bf16 out)
    const int i = (pb - 32) * 256 + threadIdx.x;  // quad index
    const float4 v = *(const float4*)&x[(size_t)i * 4];
    __bf16 o[4] = {(__bf16)v.x, (__bf16)v.y, (__bf16)v.z, (__bf16)v.w};
    *(ulong1*)&xb[(size_t)i * 4] = *(ulong1*)o;
}

// ---------------------------------------------------------------------------
// 3-phase parallel scan (deg -> off); phase C also zeroes cur.
// ---------------------------------------------------------------------------
__global__ __launch_bounds__(256) void scanA_kernel(const int* __restrict__ deg,
                                                    int* __restrict__ off,
                                                    int* __restrict__ partial, int N) {
    __shared__ int sm[256];
    const int t = threadIdx.x;
    const int i = blockIdx.x * 256 + t;
    const int v = (i < N) ? deg[i] : 0;
    sm[t] = v;
    __syncthreads();
    int val = v;
#pragma unroll
    for (int o = 1; o < 256; o <<= 1) {
        const int add = (t >= o) ? sm[t - o] : 0;
        __syncthreads();
        val += add;
        sm[t] = val;
        __syncthreads();
    }
    if (i < N) off[i] = val - v;
    if (t == 255) partial[blockIdx.x] = val;
}

__global__ __launch_bounds__(256) void scanB_kernel(int* __restrict__ partial,
                                                    int* __restrict__ off_last) {
    __shared__ int sm[256];
    const int t = threadIdx.x;
    const int v = (t < SCAN_BLOCKS) ? partial[t] : 0;
    sm[t] = v;
    __syncthreads();
    int val = v;
#pragma unroll
    for (int o = 1; o < 256; o <<= 1) {
        const int add = (t >= o) ? sm[t - o] : 0;
        __syncthreads();
        val += add;
        sm[t] = val;
        __syncthreads();
    }
    if (t < SCAN_BLOCKS) partial[t] = val - v;
    if (t == SCAN_BLOCKS - 1) *off_last = val;
}

__global__ __launch_bounds__(256) void scanC_kernel(int* __restrict__ off,
                                                    const int* __restrict__ partial,
                                                    int* __restrict__ cur, int N) {
    const int i = blockIdx.x * 256 + threadIdx.x;
    if (i < N) {
        off[i] += partial[blockIdx.x];
        cur[i] = 0;
    }
}

// ---------------------------------------------------------------------------
// gemm1: as1/ad1 = alpha-logits of (x @ W1). No C store.
// ---------------------------------------------------------------------------
__global__ __launch_bounds__(256) void gemm1_kernel(
        const float* __restrict__ A, const __bf16* __restrict__ Bh,
        const __bf16* __restrict__ Bl, const float* __restrict__ avs,
        const float* __restrict__ avd, float* __restrict__ as_out,
        float* __restrict__ ad_out, int M) {
    constexpr int NT = F1 / 16, KK = IN_DIM / 32, NH = HEADS;
    constexpr int Ncols = NT * 16;
    constexpr int K = KK * 32;
    const int tid  = threadIdx.x;
    const int wave = tid >> 6, lane = tid & 63;
    const int quad = lane >> 4, l16 = lane & 15;
    const int rowA = min((int)blockIdx.x * 64 + wave * 16 + l16, M - 1);

    f32x4 acc[NT];
#pragma unroll
    for (int t = 0; t < NT; t++) acc[t] = (f32x4){0.f, 0.f, 0.f, 0.f};

    for (int kk = 0; kk < KK; kk++) {
        const int k0 = kk * 32 + quad * 8;
        float a8[8];
        *(float4*)&a8[0] = *(const float4*)&A[(size_t)rowA * K + k0];
        *(float4*)&a8[4] = *(const float4*)&A[(size_t)rowA * K + k0 + 4];
        bf16x8 ah, al;
#pragma unroll
        for (int j = 0; j < 8; j++) {
            const __bf16 h = (__bf16)a8[j];
            ah[j] = h;
            al[j] = (__bf16)(a8[j] - (float)h);
        }
#pragma unroll
        for (int t = 0; t < NT; t++) {
            const size_t bi = ((size_t)(t * KK + kk) * 64 + lane) * 8;
            bf16x8 bhv = *(const bf16x8*)&Bh[bi];
            bf16x8 blv = *(const bf16x8*)&Bl[bi];
            acc[t] = __builtin_amdgcn_mfma_f32_16x16x32_bf16(ah, bhv, acc[t], 0, 0, 0);
            acc[t] = __builtin_amdgcn_mfma_f32_16x16x32_bf16(al, bhv, acc[t], 0, 0, 0);
            acc[t] = __builtin_amdgcn_mfma_f32_16x16x32_bf16(ah, blv, acc[t], 0, 0, 0);
        }
    }

    const int rowS = blockIdx.x * 64 + wave * 16 + quad * 4;
#pragma unroll
    for (int r = 0; r < 4; r++) {
        float ps[NH], pd[NH];
#pragma unroll
        for (int h = 0; h < NH; h++) { ps[h] = 0.f; pd[h] = 0.f; }
#pragma unroll
        for (int t = 0; t < NT; t++) {
            const int h = (t * 16) / (Ncols / NH);
            const int col = t * 16 + l16;
            ps[h] += acc[t][r] * avs[col];
            pd[h] += acc[t][r] * avd[col];
        }
#pragma unroll
        for (int o = 1; o < 16; o <<= 1) {
#pragma unroll
            for (int h = 0; h < NH; h++) {
                ps[h] += __shfl_xor(ps[h], o);
                pd[h] += __shfl_xor(pd[h], o);
            }
        }
        const int rr = rowS + r;
        if (l16 == 0 && rr < M) {
#pragma unroll
            for (int h = 0; h < NH; h++) {
                as_out[rr * NH + h] = ps[h];
                ad_out[rr * NH + h] = pd[h];
            }
        }
    }
}

// CSR scatter fused with layer-1 edge-weight computation (as1/ad1 ready).
__global__ __launch_bounds__(256) void scatter_w1_kernel(
        const int* __restrict__ ei, const int* __restrict__ off,
        int* __restrict__ cur, int* __restrict__ col, int* __restrict__ row,
        const float* __restrict__ as1, const float* __restrict__ ad1,
        float4* __restrict__ w4, int E) {
    const int e = blockIdx.x * 256 + threadIdx.x;
    if (e >= E) return;
    const int s = ei[e], d = ei[E + e];
    const int pos = atomicAdd(&cur[d], 1);
    const int slot = off[d] + pos;
    col[slot] = s;
    row[slot] = d;
    const float4 a = *(const float4*)&as1[s * HEADS];
    const float4 b = *(const float4*)&ad1[d * HEADS];
    float4 o;
    o.x = expf(lrelu(a.x + b.x));
    o.y = expf(lrelu(a.y + b.y));
    o.z = expf(lrelu(a.z + b.z));
    o.w = expf(lrelu(a.w + b.w));
    w4[slot] = o;
}

// Layer-2 edge weights (one exp per edge instead of 64).
__global__ __launch_bounds__(256) void w2_kernel(const int* __restrict__ col,
                                                 const int* __restrict__ row,
                                                 const float* __restrict__ as2,
                                                 const float* __restrict__ ad2,
                                                 float* __restrict__ w2, int E) {
    const int i = blockIdx.x * 256 + threadIdx.x;
    if (i >= E) return;
    w2[i] = expf(lrelu(as2[col[i]] + ad2[row[i]]));
}

// ---------------------------------------------------------------------------
// Layer-1 x-aggregation: one wave per dst node, bf16 x gather (4 B/lane,
// halves the dominant gather traffic), f32 weights/accumulate, 4-edge unroll.
// ---------------------------------------------------------------------------
__global__ __launch_bounds__(256) void agg1x_kernel(const int* __restrict__ off,
                                                    const int* __restrict__ col,
                                                    const float4* __restrict__ w4,
                                                    const __bf16* __restrict__ xb,
                                                    const float* __restrict__ as1,
                                                    const float* __restrict__ ad1,
                                                    float* __restrict__ aggx, int N) {
    const int w = __builtin_amdgcn_readfirstlane((blockIdx.x * 256 + threadIdx.x) >> 6);
    const int lane = threadIdx.x & 63;
    if (w >= N) return;

    float2 acc[HEADS];
    float z[HEADS];
#pragma unroll
    for (int h = 0; h < HEADS; h++) { acc[h] = make_float2(0.f, 0.f); z[h] = 0.f; }

    {   // self-loop
        const float4 asv = *(const float4*)&as1[w * HEADS];
        const float4 adv = *(const float4*)&ad1[w * HEADS];
        const bf16x2 xv = *(const bf16x2*)&xb[(size_t)w * IN_DIM + lane * 2];
        const float vx = (float)xv[0], vy = (float)xv[1];
        float ws[HEADS] = {expf(lrelu(asv.x + adv.x)), expf(lrelu(asv.y + adv.y)),
                           expf(lrelu(asv.z + adv.z)), expf(lrelu(asv.w + adv.w))};
#pragma unroll
        for (int h = 0; h < HEADS; h++) {
            acc[h].x += ws[h] * vx; acc[h].y += ws[h] * vy; z[h] += ws[h];
        }
    }
    const int jb = off[w], je = off[w + 1];
    int j = jb;
    for (; j + 3 < je; j += 4) {
        const int s0 = col[j], s1 = col[j + 1], s2 = col[j + 2], s3 = col[j + 3];
        const float4 w0 = w4[j], w1 = w4[j + 1], w2 = w4[j + 2], w3 = w4[j + 3];
        const bf16x2 b0 = *(const bf16x2*)&xb[(size_t)s0 * IN_DIM + lane * 2];
        const bf16x2 b1 = *(const bf16x2*)&xb[(size_t)s1 * IN_DIM + lane * 2];
        const bf16x2 b2 = *(const bf16x2*)&xb[(size_t)s2 * IN_DIM + lane * 2];
        const bf16x2 b3 = *(const bf16x2*)&xb[(size_t)s3 * IN_DIM + lane * 2];
        const float v0x = (float)b0[0], v0y = (float)b0[1];
        const float v1x = (float)b1[0], v1y = (float)b1[1];
        const float v2x = (float)b2[0], v2y = (float)b2[1];
        const float v3x = (float)b3[0], v3y = (float)b3[1];
        acc[0].x += w0.x * v0x + w1.x * v1x + w2.x * v2x + w3.x * v3x;
        acc[0].y += w0.x * v0y + w1.x * v1y + w2.x * v2y + w3.x * v3y;
        acc[1].x += w0.y * v0x + w1.y * v1x + w2.y * v2x + w3.y * v3x;
        acc[1].y += w0.y * v0y + w1.y * v1y + w2.y * v2y + w3.y * v3y;
        acc[2].x += w0.z * v0x + w1.z * v1x + w2.z * v2x + w3.z * v3x;
        acc[2].y += w0.z * v0y + w1.z * v1y + w2.z * v2y + w3.z * v3y;
        acc[3].x += w0.w * v0x + w1.w * v1x + w2.w * v2x + w3.w * v3x;
        acc[3].y += w0.w * v0y + w1.w * v1y + w2.w * v2y + w3.w * v3y;
        z[0] += (w0.x + w1.x) + (w2.x + w3.x);
        z[1] += (w0.y + w1.y) + (w2.y + w3.y);
        z[2] += (w0.z + w1.z) + (w2.z + w3.z);
        z[3] += (w0.w + w1.w) + (w2.w + w3.w);
    }
    for (; j < je; j++) {
        const int s0 = col[j];
        const float4 w0 = w4[j];
        const bf16x2 b0 = *(const bf16x2*)&xb[(size_t)s0 * IN_DIM + lane * 2];
        const float v0x = (float)b0[0], v0y = (float)b0[1];
        acc[0].x += w0.x * v0x; acc[0].y += w0.x * v0y; z[0] += w0.x;
        acc[1].x += w0.y * v0x; acc[1].y += w0.y * v0y; z[1] += w0.y;
        acc[2].x += w0.z * v0x; acc[2].y += w0.z * v0y; z[2] += w0.z;
        acc[3].x += w0.w * v0x; acc[3].y += w0.w * v0y; z[3] += w0.w;
    }
#pragma unroll
    for (int h = 0; h < HEADS; h++) {
        const float inv = 1.f / z[h];
        float2 o = make_float2(acc[h].x * inv, acc[h].y * inv);
        *(float2*)&aggx[((size_t)w * HEADS + h) * IN_DIM + lane * 2] = o;
    }
}

// ---------------------------------------------------------------------------
// FUSED layer-1-reconstruct + layer-2 GEMM, 16 rows/block, 4 waves.
// g2 is written as bf16 (only consumer is agg2's gather) — halves its bytes.
// ---------------------------------------------------------------------------
__global__ __launch_bounds__(256) void gemm12_kernel(
        const float* __restrict__ aggx,
        const __bf16* __restrict__ B1h, const __bf16* __restrict__ B1l,
        const float* __restrict__ b1,
        const __bf16* __restrict__ B2h, const __bf16* __restrict__ B2l,
        const float* __restrict__ avs, const float* __restrict__ avd,
        __bf16* __restrict__ g2b, float* __restrict__ as_out,
        float* __restrict__ ad_out, int M) {
    __shared__ float sm[16 * LDP16];
    __shared__ float pps[4][16], pdd[4][16];
    const int tid  = threadIdx.x;
    const int wave = tid >> 6, lane = tid & 63;
    const int quad = lane >> 4, l16 = lane & 15;
    const int row0 = blockIdx.x * 16;
    const int rowA = min(row0 + l16, M - 1);

    // ---- phase 1: this wave's head = `wave` ----
    {
        f32x4 acc1[4];
#pragma unroll
        for (int t = 0; t < 4; t++) acc1[t] = (f32x4){0.f, 0.f, 0.f, 0.f};
        const float* Arow = aggx + ((size_t)rowA * HEADS + wave) * IN_DIM;
#pragma unroll
        for (int kk = 0; kk < 4; kk++) {
            const int k0 = kk * 32 + quad * 8;
            float a8[8];
            *(float4*)&a8[0] = *(const float4*)&Arow[k0];
            *(float4*)&a8[4] = *(const float4*)&Arow[k0 + 4];
            bf16x8 ah, al;
#pragma unroll
            for (int j = 0; j < 8; j++) {
                const __bf16 hh = (__bf16)a8[j];
                ah[j] = hh;
                al[j] = (__bf16)(a8[j] - (float)hh);
            }
#pragma unroll
            for (int t = 0; t < 4; t++) {
                const size_t bi = (size_t)wave * W1_FRAG +
                                  ((size_t)(t * 4 + kk) * 64 + lane) * 8;
                bf16x8 bhv = *(const bf16x8*)&B1h[bi];
                bf16x8 blv = *(const bf16x8*)&B1l[bi];
                acc1[t] = __builtin_amdgcn_mfma_f32_16x16x32_bf16(ah, bhv, acc1[t], 0, 0, 0);
                acc1[t] = __builtin_amdgcn_mfma_f32_16x16x32_bf16(al, bhv, acc1[t], 0, 0, 0);
                acc1[t] = __builtin_amdgcn_mfma_f32_16x16x32_bf16(ah, blv, acc1[t], 0, 0, 0);
            }
        }
#pragma unroll
        for (int t = 0; t < 4; t++) {
            const int c = wave * 64 + t * 16 + l16;
            const float bb = b1[c];
#pragma unroll
            for (int r = 0; r < 4; r++) {
                sm[(quad * 4 + r) * LDP16 + c] = eluf(acc1[t][r] + bb);
            }
        }
    }
    __syncthreads();

    // ---- phase 2: this wave's output cols = tiles {2*wave, 2*wave+1} ----
    f32x4 acc2[2];
#pragma unroll
    for (int t = 0; t < 2; t++) acc2[t] = (f32x4){0.f, 0.f, 0.f, 0.f};
    const int arow = l16 * LDP16;
#pragma unroll
    for (int kk = 0; kk < 8; kk++) {
        const int k0 = kk * 32 + quad * 8;
        float a8[8];
        *(float4*)&a8[0] = *(const float4*)&sm[arow + k0];
        *(float4*)&a8[4] = *(const float4*)&sm[arow + k0 + 4];
        bf16x8 ah, al;
#pragma unroll
        for (int j = 0; j < 8; j++) {
            const __bf16 hh = (__bf16)a8[j];
            ah[j] = hh;
            al[j] = (__bf16)(a8[j] - (float)hh);
        }
#pragma unroll
        for (int tt = 0; tt < 2; tt++) {
            const int t = wave * 2 + tt;
            const size_t bi = ((size_t)(t * 8 + kk) * 64 + lane) * 8;
            bf16x8 bhv = *(const bf16x8*)&B2h[bi];
            bf16x8 blv = *(const bf16x8*)&B2l[bi];
            acc2[tt] = __builtin_amdgcn_mfma_f32_16x16x32_bf16(ah, bhv, acc2[tt], 0, 0, 0);
            acc2[tt] = __builtin_amdgcn_mfma_f32_16x16x32_bf16(al, bhv, acc2[tt], 0, 0, 0);
            acc2[tt] = __builtin_amdgcn_mfma_f32_16x16x32_bf16(ah, blv, acc2[tt], 0, 0, 0);
        }
    }

    // store g2 (bf16) + alpha2 logit partials (f32, exact from acc2)
    const int rowS = row0 + quad * 4;
#pragma unroll
    for (int tt = 0; tt < 2; tt++) {
        const int t = wave * 2 + tt;
#pragma unroll
        for (int r = 0; r < 4; r++) {
            const int rr = rowS + r;
            if (rr < M) g2b[(size_t)rr * EMB + t * 16 + l16] = (__bf16)acc2[tt][r];
        }
    }
#pragma unroll
    for (int r = 0; r < 4; r++) {
        float ps = 0.f, pd = 0.f;
#pragma unroll
        for (int tt = 0; tt < 2; tt++) {
            const int c = (wave * 2 + tt) * 16 + l16;
            ps += acc2[tt][r] * avs[c];
            pd += acc2[tt][r] * avd[c];
        }
#pragma unroll
        for (int o = 1; o < 16; o <<= 1) {
            ps += __shfl_xor(ps, o);
            pd += __shfl_xor(pd, o);
        }
        if (l16 == 0) {
            pps[wave][quad * 4 + r] = ps;
            pdd[wave][quad * 4 + r] = pd;
        }
    }
    __syncthreads();
    if (tid < 16) {
        const int rr = row0 + tid;
        if (rr < M) {
            as_out[rr] = pps[0][tid] + pps[1][tid] + pps[2][tid] + pps[3][tid];
            ad_out[rr] = pdd[0][tid] + pdd[1][tid] + pdd[2][tid] + pdd[3][tid];
        }
    }
}

// ---------------------------------------------------------------------------
// Layer-2 aggregation: one wave per dst node, bf16 g2 gather, f32 weights.
// ---------------------------------------------------------------------------
__global__ __launch_bounds__(256) void agg2_kernel(const int* __restrict__ off,
                                                   const int* __restrict__ col,
                                                   const float* __restrict__ w2,
                                                   const __bf16* __restrict__ g2b,
                                                   const float* __restrict__ as2,
                                                   const float* __restrict__ ad2,
                                                   float* __restrict__ out2, int N) {
    const int w = __builtin_amdgcn_readfirstlane((blockIdx.x * 256 + threadIdx.x) >> 6);
    const int lane = threadIdx.x & 63;
    if (w >= N) return;

    float2 acc = make_float2(0.f, 0.f);
    float z = 0.f;
    {   // self-loop
        const float wt = expf(lrelu(as2[w] + ad2[w]));
        const bf16x2 hv = *(const bf16x2*)&g2b[(size_t)w * EMB + lane * 2];
        acc.x += wt * (float)hv[0]; acc.y += wt * (float)hv[1];
        z += wt;
    }
    const int jb = off[w], je = off[w + 1];
    int j = jb;
    for (; j + 3 < je; j += 4) {
        const int s0 = col[j], s1 = col[j + 1], s2 = col[j + 2], s3 = col[j + 3];
        const float w0 = w2[j], w1 = w2[j + 1], w2v = w2[j + 2], w3 = w2[j + 3];
        const bf16x2 b0 = *(const bf16x2*)&g2b[(size_t)s0 * EMB + lane * 2];
        const bf16x2 b1 = *(const bf16x2*)&g2b[(size_t)s1 * EMB + lane * 2];
        const bf16x2 b2 = *(const bf16x2*)&g2b[(size_t)s2 * EMB + lane * 2];
        const bf16x2 b3 = *(const bf16x2*)&g2b[(size_t)s3 * EMB + lane * 2];
        acc.x += w0 * (float)b0[0] + w1 * (float)b1[0] + w2v * (float)b2[0] + w3 * (float)b3[0];
        acc.y += w0 * (float)b0[1] + w1 * (float)b1[1] + w2v * (float)b2[1] + w3 * (float)b3[1];
        z += (w0 + w1) + (w2v + w3);
    }
    for (; j < je; j++) {
        const int s0 = col[j];
        const float w0 = w2[j];
        const bf16x2 b0 = *(const bf16x2*)&g2b[(size_t)s0 * EMB + lane * 2];
        acc.x += w0 * (float)b0[0]; acc.y += w0 * (float)b0[1];
        z += w0;
    }
    const float inv = 1.f / z;
    float2 o = make_float2(acc.x * inv, acc.y * inv);
    *(float2*)&out2[(size_t)w * EMB + lane * 2] = o;
}

// ---------------------------------------------------------------------------
// Global mean pool (782-block run-length form) + divide.
// ---------------------------------------------------------------------------
__global__ __launch_bounds__(128) void pool_kernel(const float* __restrict__ out2,
                                                   const float* __restrict__ b2,
                                                   const int* __restrict__ batch,
                                                   float* __restrict__ pool,
                                                   float* __restrict__ cnt, int N) {
    const int c = threadIdx.x;
    const int n0 = blockIdx.x * 64;
    const int nend = min(n0 + 64, N);
    const float bias = b2[c];
    float acc = 0.f, cacc = 0.f;
    int curg = batch[n0];
    for (int n = n0; n < nend; n++) {
        const int g = batch[n];
        if (g != curg) {
            atomicAdd(&pool[curg * EMB + c], acc);
            if (c == 0) atomicAdd(&cnt[curg], cacc);
            acc = 0.f; cacc = 0.f; curg = g;
        }
        float v = out2[(size_t)n * EMB + c] + bias;
        v = v > 0.f ? v : expm1f(v);
        acc += v;
        cacc += 1.f;
    }
    atomicAdd(&pool[curg * EMB + c], acc);
    if (c == 0) atomicAdd(&cnt[curg], cacc);
}

__global__ __launch_bounds__(256) void div_kernel(const float* __restrict__ pool,
                                                  const float* __restrict__ cnt,
                                                  float* __restrict__ out) {
    const int i = blockIdx.x * 256 + threadIdx.x;
    out[i] = pool[i] / fmaxf(cnt[i >> 7], 1.f);
}

// ---------------------------------------------------------------------------
extern "C" void kernel_launch(void* const* d_in, const int* in_sizes, int n_in,
                              void* d_out, int out_size, void* d_ws, size_t ws_size,
                              hipStream_t stream) {
    const float* x      = (const float*)d_in[0];
    const int*   ei     = (const int*)d_in[1];
    const int*   batch  = (const int*)d_in[3];
    const float* W1     = (const float*)d_in[4];
    const float* a_src1 = (const float*)d_in[5];
    const float* a_dst1 = (const float*)d_in[6];
    const float* b1     = (const float*)d_in[7];
    const float* W2     = (const float*)d_in[8];
    const float* a_src2 = (const float*)d_in[9];
    const float* a_dst2 = (const float*)d_in[10];
    const float* b2     = (const float*)d_in[11];
    float* out = (float*)d_out;

    const int N = N_NODES, E = N_EDGES;

    size_t cur_off = 0;
    auto carve = [&](size_t bytes) {
        size_t o = cur_off;
        cur_off = (cur_off + bytes + 255) & ~(size_t)255;
        return (char*)d_ws + o;
    };
    // zero-init region: deg + pool + cnt
    int* deg     = (int*)carve((size_t)N * 4);
    float* pool  = (float*)carve((size_t)N_GRAPHS * EMB * 4);
    float* cnt   = (float*)carve((size_t)N_GRAPHS * 4);
    const size_t zero_bytes = cur_off;
    int* curp    = (int*)carve((size_t)N * 4);
    int* partial = (int*)carve((size_t)SCAN_BLOCKS * 4);
    __bf16* B1h  = (__bf16*)carve((size_t)HEADS * W1_FRAG * 2);
    __bf16* B1l  = (__bf16*)carve((size_t)HEADS * W1_FRAG * 2);
    __bf16* B2h  = (__bf16*)carve((size_t)F1 * EMB * 2);
    __bf16* B2l  = (__bf16*)carve((size_t)F1 * EMB * 2);
    __bf16* xb   = (__bf16*)carve((size_t)N * IN_DIM * 2);
    int* off     = (int*)carve((size_t)(N + 1) * 4);
    int* col     = (int*)carve((size_t)E * 4);
    int* rowd    = (int*)carve((size_t)E * 4);
    float4* w4   = (float4*)carve((size_t)E * 16);
    float* w2    = (float*)carve((size_t)E * 4);
    float* aggx  = (float*)carve((size_t)N * HEADS * IN_DIM * 4);
    __bf16* g2b  = (__bf16*)carve((size_t)N * EMB * 2);
    float* out2  = (float*)carve((size_t)N * EMB * 4);
    float* as1   = (float*)carve((size_t)N * HEADS * 4);
    float* ad1   = (float*)carve((size_t)N * HEADS * 4);
    float* as2   = (float*)carve((size_t)N * 4);
    float* ad2   = (float*)carve((size_t)N * 4);

    hipMemsetAsync(d_ws, 0, zero_bytes, stream);

    prep_kernel<<<DEG_BLOCKS + 32 + XCONV_BLOCKS, 256, 0, stream>>>(
        ei, deg, W1, B1h, B1l, W2, B2h, B2l, x, xb);

    scanA_kernel<<<SCAN_BLOCKS, 256, 0, stream>>>(deg, off, partial, N);
    scanB_kernel<<<1, 256, 0, stream>>>(partial, &off[N]);
    scanC_kernel<<<SCAN_BLOCKS, 256, 0, stream>>>(off, partial, curp, N);

    // gemm1 (x -> as1/ad1), then scatter fused with edge-weight computation
    gemm1_kernel<<<(N + 63) / 64, 256, 0, stream>>>(x, B1h, B1l, a_src1, a_dst1,
                                                    as1, ad1, N);
    scatter_w1_kernel<<<DEG_BLOCKS, 256, 0, stream>>>(ei, off, curp, col, rowd,
                                                      as1, ad1, w4, E);

    agg1x_kernel<<<(N + 3) / 4, 256, 0, stream>>>(off, col, w4, xb, as1, ad1, aggx, N);

    // fused: (aggx @ W1 -> ELU -> @ W2) + alpha2; g2 stored bf16
    gemm12_kernel<<<(N + 15) / 16, 256, 0, stream>>>(aggx, B1h, B1l, b1, B2h, B2l,
                                                     a_src2, a_dst2, g2b, as2, ad2, N);

    w2_kernel<<<DEG_BLOCKS, 256, 0, stream>>>(col, rowd, as2, ad2, w2, E);
    agg2_kernel<<<(N + 3) / 4, 256, 0, stream>>>(off, col, w2, g2b, as2, ad2, out2, N);

    pool_kernel<<<(N + 63) / 64, 128, 0, stream>>>(out2, b2, batch, pool, cnt, N);
    div_kernel<<<(N_GRAPHS * EMB) / 256, 256, 0, stream>>>(pool, cnt, out);
}

// Round 13
// 373.172 us; speedup vs baseline: 1.3017x; 1.0194x over previous
//
#include <hip/hip_runtime.h>
#include <hip/hip_bf16.h>
#include <cstddef>

// Problem constants (fixed-shape problem)
constexpr int N_NODES = 50000;
constexpr int N_EDGES = 800000;
constexpr int IN_DIM  = 128;
constexpr int HID     = 64;
constexpr int HEADS   = 4;
constexpr int F1      = HEADS * HID;  // 256
constexpr int EMB     = 128;
constexpr int N_GRAPHS = 64;

constexpr int DEG_BLOCKS   = (N_EDGES + 255) / 256;          // 3125
constexpr int SCAN_BLOCKS  = (N_NODES + 255) / 256;          // 196
constexpr int XCONV_BLOCKS = (N_NODES * IN_DIM / 4) / 256;   // 6250 (exact)
// per-head W1 fragment size (NT=4, KK=4): 4*4*64*8 bf16 elements
constexpr int W1_FRAG = 4 * 4 * 64 * 8;                      // 8192
// gemm12 LDS tile stride in bf16 elems: 264*2 = 528 B rows (16 B aligned for
// ds_read_b128; 132 dwords mod 32 = 4 -> ~2-way bank alias, free per m136)
constexpr int LDSB = 264;

typedef __bf16 bf16x8 __attribute__((ext_vector_type(8)));
typedef __bf16 bf16x2 __attribute__((ext_vector_type(2)));
typedef float  f32x4  __attribute__((ext_vector_type(4)));

__device__ __forceinline__ float lrelu(float x) { return x > 0.f ? x : 0.2f * x; }
__device__ __forceinline__ float eluf(float x)  { return x > 0.f ? x : expm1f(x); }

// ---------------------------------------------------------------------------
// Pack a [K x 16*NT] submatrix of B (leading dim ld, origin col0) into
// per-lane MFMA B-fragments, split hi/lo bf16.
// ---------------------------------------------------------------------------
__device__ __forceinline__ void pack_frag(const float* __restrict__ B,
                                          __bf16* __restrict__ hi,
                                          __bf16* __restrict__ lo,
                                          int pblk, int NT, int KK, int ld, int col0) {
    const int gid = pblk * 256 + threadIdx.x;
    if (gid >= NT * KK * 64) return;
    const int lane = gid & 63;
    const int rem  = gid >> 6;
    const int kk   = rem % KK;
    const int t    = rem / KK;
    const int n    = col0 + t * 16 + (lane & 15);
    const int k0   = kk * 32 + (lane >> 4) * 8;
#pragma unroll
    for (int j = 0; j < 8; j++) {
        const float v = B[(size_t)(k0 + j) * ld + n];
        const __bf16 h = (__bf16)v;
        hi[(size_t)gid * 8 + j] = h;
        lo[(size_t)gid * 8 + j] = (__bf16)(v - (float)h);
    }
}

// ---------------------------------------------------------------------------
// prep: [deg histogram | pack W1 | pack W2 | x -> bf16 copy] by block range.
// ---------------------------------------------------------------------------
__global__ __launch_bounds__(256) void prep_kernel(const int* __restrict__ ei,
                                                   int* __restrict__ deg,
                                                   const float* __restrict__ W1,
                                                   __bf16* __restrict__ B1h,
                                                   __bf16* __restrict__ B1l,
                                                   const float* __restrict__ W2,
                                                   __bf16* __restrict__ B2h,
                                                   __bf16* __restrict__ B2l,
                                                   const float* __restrict__ x,
                                                   __bf16* __restrict__ xb) {
    const int b = blockIdx.x;
    if (b < DEG_BLOCKS) {
        const int e = b * 256 + threadIdx.x;
        if (e < N_EDGES) atomicAdd(&deg[ei[N_EDGES + e]], 1);
        return;
    }
    const int pb = b - DEG_BLOCKS;
    if (pb < 16) {
        const int head = pb >> 2;
        pack_frag(W1, B1h + head * W1_FRAG, B1l + head * W1_FRAG,
                  pb & 3, 4, 4, F1, head * HID);
        return;
    }
    if (pb < 32) {
        pack_frag(W2, B2h, B2l, pb - 16, 8, 8, EMB, 0);
        return;
    }
    // x -> bf16 (float4 in, 4x bf16 out)
    const int i = (pb - 32) * 256 + threadIdx.x;  // quad index
    const float4 v = *(const float4*)&x[(size_t)i * 4];
    __bf16 o[4] = {(__bf16)v.x, (__bf16)v.y, (__bf16)v.z, (__bf16)v.w};
    *(ulong1*)&xb[(size_t)i * 4] = *(ulong1*)o;
}

// ---------------------------------------------------------------------------
// 3-phase parallel scan (deg -> off); phase C also zeroes cur.
// ---------------------------------------------------------------------------
__global__ __launch_bounds__(256) void scanA_kernel(const int* __restrict__ deg,
                                                    int* __restrict__ off,
                                                    int* __restrict__ partial, int N) {
    __shared__ int sm[256];
    const int t = threadIdx.x;
    const int i = blockIdx.x * 256 + t;
    const int v = (i < N) ? deg[i] : 0;
    sm[t] = v;
    __syncthreads();
    int val = v;
#pragma unroll
    for (int o = 1; o < 256; o <<= 1) {
        const int add = (t >= o) ? sm[t - o] : 0;
        __syncthreads();
        val += add;
        sm[t] = val;
        __syncthreads();
    }
    if (i < N) off[i] = val - v;
    if (t == 255) partial[blockIdx.x] = val;
}

__global__ __launch_bounds__(256) void scanB_kernel(int* __restrict__ partial,
                                                    int* __restrict__ off_last) {
    __shared__ int sm[256];
    const int t = threadIdx.x;
    const int v = (t < SCAN_BLOCKS) ? partial[t] : 0;
    sm[t] = v;
    __syncthreads();
    int val = v;
#pragma unroll
    for (int o = 1; o < 256; o <<= 1) {
        const int add = (t >= o) ? sm[t - o] : 0;
        __syncthreads();
        val += add;
        sm[t] = val;
        __syncthreads();
    }
    if (t < SCAN_BLOCKS) partial[t] = val - v;
    if (t == SCAN_BLOCKS - 1) *off_last = val;
}

__global__ __launch_bounds__(256) void scanC_kernel(int* __restrict__ off,
                                                    const int* __restrict__ partial,
                                                    int* __restrict__ cur, int N) {
    const int i = blockIdx.x * 256 + threadIdx.x;
    if (i < N) {
        off[i] += partial[blockIdx.x];
        cur[i] = 0;
    }
}

// ---------------------------------------------------------------------------
// gemm1: as1/ad1 = alpha-logits of (x @ W1). No C store.
// ---------------------------------------------------------------------------
__global__ __launch_bounds__(256) void gemm1_kernel(
        const float* __restrict__ A, const __bf16* __restrict__ Bh,
        const __bf16* __restrict__ Bl, const float* __restrict__ avs,
        const float* __restrict__ avd, float* __restrict__ as_out,
        float* __restrict__ ad_out, int M) {
    constexpr int NT = F1 / 16, KK = IN_DIM / 32, NH = HEADS;
    constexpr int Ncols = NT * 16;
    constexpr int K = KK * 32;
    const int tid  = threadIdx.x;
    const int wave = tid >> 6, lane = tid & 63;
    const int quad = lane >> 4, l16 = lane & 15;
    const int rowA = min((int)blockIdx.x * 64 + wave * 16 + l16, M - 1);

    f32x4 acc[NT];
#pragma unroll
    for (int t = 0; t < NT; t++) acc[t] = (f32x4){0.f, 0.f, 0.f, 0.f};

    for (int kk = 0; kk < KK; kk++) {
        const int k0 = kk * 32 + quad * 8;
        float a8[8];
        *(float4*)&a8[0] = *(const float4*)&A[(size_t)rowA * K + k0];
        *(float4*)&a8[4] = *(const float4*)&A[(size_t)rowA * K + k0 + 4];
        bf16x8 ah, al;
#pragma unroll
        for (int j = 0; j < 8; j++) {
            const __bf16 h = (__bf16)a8[j];
            ah[j] = h;
            al[j] = (__bf16)(a8[j] - (float)h);
        }
#pragma unroll
        for (int t = 0; t < NT; t++) {
            const size_t bi = ((size_t)(t * KK + kk) * 64 + lane) * 8;
            bf16x8 bhv = *(const bf16x8*)&Bh[bi];
            bf16x8 blv = *(const bf16x8*)&Bl[bi];
            acc[t] = __builtin_amdgcn_mfma_f32_16x16x32_bf16(ah, bhv, acc[t], 0, 0, 0);
            acc[t] = __builtin_amdgcn_mfma_f32_16x16x32_bf16(al, bhv, acc[t], 0, 0, 0);
            acc[t] = __builtin_amdgcn_mfma_f32_16x16x32_bf16(ah, blv, acc[t], 0, 0, 0);
        }
    }

    const int rowS = blockIdx.x * 64 + wave * 16 + quad * 4;
#pragma unroll
    for (int r = 0; r < 4; r++) {
        float ps[NH], pd[NH];
#pragma unroll
        for (int h = 0; h < NH; h++) { ps[h] = 0.f; pd[h] = 0.f; }
#pragma unroll
        for (int t = 0; t < NT; t++) {
            const int h = (t * 16) / (Ncols / NH);
            const int col = t * 16 + l16;
            ps[h] += acc[t][r] * avs[col];
            pd[h] += acc[t][r] * avd[col];
        }
#pragma unroll
        for (int o = 1; o < 16; o <<= 1) {
#pragma unroll
            for (int h = 0; h < NH; h++) {
                ps[h] += __shfl_xor(ps[h], o);
                pd[h] += __shfl_xor(pd[h], o);
            }
        }
        const int rr = rowS + r;
        if (l16 == 0 && rr < M) {
#pragma unroll
            for (int h = 0; h < NH; h++) {
                as_out[rr * NH + h] = ps[h];
                ad_out[rr * NH + h] = pd[h];
            }
        }
    }
}

// CSR scatter fused with layer-1 edge-weight computation (as1/ad1 ready).
__global__ __launch_bounds__(256) void scatter_w1_kernel(
        const int* __restrict__ ei, const int* __restrict__ off,
        int* __restrict__ cur, int* __restrict__ col, int* __restrict__ row,
        const float* __restrict__ as1, const float* __restrict__ ad1,
        float4* __restrict__ w4, int E) {
    const int e = blockIdx.x * 256 + threadIdx.x;
    if (e >= E) return;
    const int s = ei[e], d = ei[E + e];
    const int pos = atomicAdd(&cur[d], 1);
    const int slot = off[d] + pos;
    col[slot] = s;
    row[slot] = d;
    const float4 a = *(const float4*)&as1[s * HEADS];
    const float4 b = *(const float4*)&ad1[d * HEADS];
    float4 o;
    o.x = expf(lrelu(a.x + b.x));
    o.y = expf(lrelu(a.y + b.y));
    o.z = expf(lrelu(a.z + b.z));
    o.w = expf(lrelu(a.w + b.w));
    w4[slot] = o;
}

// Layer-2 edge weights (one exp per edge instead of 64).
__global__ __launch_bounds__(256) void w2_kernel(const int* __restrict__ col,
                                                 const int* __restrict__ row,
                                                 const float* __restrict__ as2,
                                                 const float* __restrict__ ad2,
                                                 float* __restrict__ w2, int E) {
    const int i = blockIdx.x * 256 + threadIdx.x;
    if (i >= E) return;
    w2[i] = expf(lrelu(as2[col[i]] + ad2[row[i]]));
}

// ---------------------------------------------------------------------------
// Layer-1 x-aggregation: bf16 x gather, f32 accumulate; output pre-split into
// bf16 hi/lo planes so gemm12 loads MFMA A-fragments with ZERO repack VALU
// (the split math is bit-identical to what gemm12 previously did in-kernel).
// ---------------------------------------------------------------------------
__global__ __launch_bounds__(256) void agg1x_kernel(const int* __restrict__ off,
                                                    const int* __restrict__ col,
                                                    const float4* __restrict__ w4,
                                                    const __bf16* __restrict__ xb,
                                                    const float* __restrict__ as1,
                                                    const float* __restrict__ ad1,
                                                    __bf16* __restrict__ aggxh,
                                                    __bf16* __restrict__ aggxl, int N) {
    const int w = __builtin_amdgcn_readfirstlane((blockIdx.x * 256 + threadIdx.x) >> 6);
    const int lane = threadIdx.x & 63;
    if (w >= N) return;

    float2 acc[HEADS];
    float z[HEADS];
#pragma unroll
    for (int h = 0; h < HEADS; h++) { acc[h] = make_float2(0.f, 0.f); z[h] = 0.f; }

    {   // self-loop
        const float4 asv = *(const float4*)&as1[w * HEADS];
        const float4 adv = *(const float4*)&ad1[w * HEADS];
        const bf16x2 xv = *(const bf16x2*)&xb[(size_t)w * IN_DIM + lane * 2];
        const float vx = (float)xv[0], vy = (float)xv[1];
        float ws[HEADS] = {expf(lrelu(asv.x + adv.x)), expf(lrelu(asv.y + adv.y)),
                           expf(lrelu(asv.z + adv.z)), expf(lrelu(asv.w + adv.w))};
#pragma unroll
        for (int h = 0; h < HEADS; h++) {
            acc[h].x += ws[h] * vx; acc[h].y += ws[h] * vy; z[h] += ws[h];
        }
    }
    const int jb = off[w], je = off[w + 1];
    int j = jb;
    for (; j + 3 < je; j += 4) {
        const int s0 = col[j], s1 = col[j + 1], s2 = col[j + 2], s3 = col[j + 3];
        const float4 w0 = w4[j], w1 = w4[j + 1], w2 = w4[j + 2], w3 = w4[j + 3];
        const bf16x2 b0 = *(const bf16x2*)&xb[(size_t)s0 * IN_DIM + lane * 2];
        const bf16x2 b1 = *(const bf16x2*)&xb[(size_t)s1 * IN_DIM + lane * 2];
        const bf16x2 b2 = *(const bf16x2*)&xb[(size_t)s2 * IN_DIM + lane * 2];
        const bf16x2 b3 = *(const bf16x2*)&xb[(size_t)s3 * IN_DIM + lane * 2];
        const float v0x = (float)b0[0], v0y = (float)b0[1];
        const float v1x = (float)b1[0], v1y = (float)b1[1];
        const float v2x = (float)b2[0], v2y = (float)b2[1];
        const float v3x = (float)b3[0], v3y = (float)b3[1];
        acc[0].x += w0.x * v0x + w1.x * v1x + w2.x * v2x + w3.x * v3x;
        acc[0].y += w0.x * v0y + w1.x * v1y + w2.x * v2y + w3.x * v3y;
        acc[1].x += w0.y * v0x + w1.y * v1x + w2.y * v2x + w3.y * v3x;
        acc[1].y += w0.y * v0y + w1.y * v1y + w2.y * v2y + w3.y * v3y;
        acc[2].x += w0.z * v0x + w1.z * v1x + w2.z * v2x + w3.z * v3x;
        acc[2].y += w0.z * v0y + w1.z * v1y + w2.z * v2y + w3.z * v3y;
        acc[3].x += w0.w * v0x + w1.w * v1x + w2.w * v2x + w3.w * v3x;
        acc[3].y += w0.w * v0y + w1.w * v1y + w2.w * v2y + w3.w * v3y;
        z[0] += (w0.x + w1.x) + (w2.x + w3.x);
        z[1] += (w0.y + w1.y) + (w2.y + w3.y);
        z[2] += (w0.z + w1.z) + (w2.z + w3.z);
        z[3] += (w0.w + w1.w) + (w2.w + w3.w);
    }
    for (; j < je; j++) {
        const int s0 = col[j];
        const float4 w0 = w4[j];
        const bf16x2 b0 = *(const bf16x2*)&xb[(size_t)s0 * IN_DIM + lane * 2];
        const float v0x = (float)b0[0], v0y = (float)b0[1];
        acc[0].x += w0.x * v0x; acc[0].y += w0.x * v0y; z[0] += w0.x;
        acc[1].x += w0.y * v0x; acc[1].y += w0.y * v0y; z[1] += w0.y;
        acc[2].x += w0.z * v0x; acc[2].y += w0.z * v0y; z[2] += w0.z;
        acc[3].x += w0.w * v0x; acc[3].y += w0.w * v0y; z[3] += w0.w;
    }
#pragma unroll
    for (int h = 0; h < HEADS; h++) {
        const float inv = 1.f / z[h];
        const float vx = acc[h].x * inv, vy = acc[h].y * inv;
        const __bf16 hx = (__bf16)vx, hy = (__bf16)vy;
        bf16x2 hv = {hx, hy};
        bf16x2 lv = {(__bf16)(vx - (float)hx), (__bf16)(vy - (float)hy)};
        const size_t o = ((size_t)w * HEADS + h) * IN_DIM + lane * 2;
        *(bf16x2*)&aggxh[o] = hv;
        *(bf16x2*)&aggxl[o] = lv;
    }
}

// ---------------------------------------------------------------------------
// FUSED layer-1-reconstruct + layer-2 GEMM, 16 rows/block, 4 waves.
// A-operands (aggx) and the inter-layer LDS tile are pre-split bf16 hi/lo:
// fragments load directly (ds_read_b128/global b128), no repack VALU.
// ---------------------------------------------------------------------------
__global__ __launch_bounds__(256) void gemm12_kernel(
        const __bf16* __restrict__ aggxh, const __bf16* __restrict__ aggxl,
        const __bf16* __restrict__ B1h, const __bf16* __restrict__ B1l,
        const float* __restrict__ b1,
        const __bf16* __restrict__ B2h, const __bf16* __restrict__ B2l,
        const float* __restrict__ avs, const float* __restrict__ avd,
        __bf16* __restrict__ g2b, float* __restrict__ as_out,
        float* __restrict__ ad_out, int M) {
    __shared__ __bf16 smh[16 * LDSB];
    __shared__ __bf16 sml[16 * LDSB];
    __shared__ float pps[4][16], pdd[4][16];
    const int tid  = threadIdx.x;
    const int wave = tid >> 6, lane = tid & 63;
    const int quad = lane >> 4, l16 = lane & 15;
    const int row0 = blockIdx.x * 16;
    const int rowA = min(row0 + l16, M - 1);

    // ---- phase 1: this wave's head = `wave`; A-fragments direct from planes
    {
        f32x4 acc1[4];
#pragma unroll
        for (int t = 0; t < 4; t++) acc1[t] = (f32x4){0.f, 0.f, 0.f, 0.f};
        const size_t abase = ((size_t)rowA * HEADS + wave) * IN_DIM;
#pragma unroll
        for (int kk = 0; kk < 4; kk++) {
            const int k0 = kk * 32 + quad * 8;
            bf16x8 ah = *(const bf16x8*)&aggxh[abase + k0];
            bf16x8 al = *(const bf16x8*)&aggxl[abase + k0];
#pragma unroll
            for (int t = 0; t < 4; t++) {
                const size_t bi = (size_t)wave * W1_FRAG +
                                  ((size_t)(t * 4 + kk) * 64 + lane) * 8;
                bf16x8 bhv = *(const bf16x8*)&B1h[bi];
                bf16x8 blv = *(const bf16x8*)&B1l[bi];
                acc1[t] = __builtin_amdgcn_mfma_f32_16x16x32_bf16(ah, bhv, acc1[t], 0, 0, 0);
                acc1[t] = __builtin_amdgcn_mfma_f32_16x16x32_bf16(al, bhv, acc1[t], 0, 0, 0);
                acc1[t] = __builtin_amdgcn_mfma_f32_16x16x32_bf16(ah, blv, acc1[t], 0, 0, 0);
            }
        }
        // ELU(+b1) -> LDS hi/lo planes (split once here, consumed raw below)
#pragma unroll
        for (int t = 0; t < 4; t++) {
            const int c = wave * 64 + t * 16 + l16;
            const float bb = b1[c];
#pragma unroll
            for (int r = 0; r < 4; r++) {
                const float v = eluf(acc1[t][r] + bb);
                const __bf16 hh = (__bf16)v;
                smh[(quad * 4 + r) * LDSB + c] = hh;
                sml[(quad * 4 + r) * LDSB + c] = (__bf16)(v - (float)hh);
            }
        }
    }
    __syncthreads();

    // ---- phase 2: this wave's output cols = tiles {2*wave, 2*wave+1} ----
    f32x4 acc2[2];
#pragma unroll
    for (int t = 0; t < 2; t++) acc2[t] = (f32x4){0.f, 0.f, 0.f, 0.f};
    const int arow = l16 * LDSB;
#pragma unroll
    for (int kk = 0; kk < 8; kk++) {
        const int k0 = kk * 32 + quad * 8;
        bf16x8 ah = *(const bf16x8*)&smh[arow + k0];
        bf16x8 al = *(const bf16x8*)&sml[arow + k0];
#pragma unroll
        for (int tt = 0; tt < 2; tt++) {
            const int t = wave * 2 + tt;
            const size_t bi = ((size_t)(t * 8 + kk) * 64 + lane) * 8;
            bf16x8 bhv = *(const bf16x8*)&B2h[bi];
            bf16x8 blv = *(const bf16x8*)&B2l[bi];
            acc2[tt] = __builtin_amdgcn_mfma_f32_16x16x32_bf16(ah, bhv, acc2[tt], 0, 0, 0);
            acc2[tt] = __builtin_amdgcn_mfma_f32_16x16x32_bf16(al, bhv, acc2[tt], 0, 0, 0);
            acc2[tt] = __builtin_amdgcn_mfma_f32_16x16x32_bf16(ah, blv, acc2[tt], 0, 0, 0);
        }
    }

    // store g2 (bf16) + alpha2 logit partials (f32, exact from acc2)
    const int rowS = row0 + quad * 4;
#pragma unroll
    for (int tt = 0; tt < 2; tt++) {
        const int t = wave * 2 + tt;
#pragma unroll
        for (int r = 0; r < 4; r++) {
            const int rr = rowS + r;
            if (rr < M) g2b[(size_t)rr * EMB + t * 16 + l16] = (__bf16)acc2[tt][r];
        }
    }
#pragma unroll
    for (int r = 0; r < 4; r++) {
        float ps = 0.f, pd = 0.f;
#pragma unroll
        for (int tt = 0; tt < 2; tt++) {
            const int c = (wave * 2 + tt) * 16 + l16;
            ps += acc2[tt][r] * avs[c];
            pd += acc2[tt][r] * avd[c];
        }
#pragma unroll
        for (int o = 1; o < 16; o <<= 1) {
            ps += __shfl_xor(ps, o);
            pd += __shfl_xor(pd, o);
        }
        if (l16 == 0) {
            pps[wave][quad * 4 + r] = ps;
            pdd[wave][quad * 4 + r] = pd;
        }
    }
    __syncthreads();
    if (tid < 16) {
        const int rr = row0 + tid;
        if (rr < M) {
            as_out[rr] = pps[0][tid] + pps[1][tid] + pps[2][tid] + pps[3][tid];
            ad_out[rr] = pdd[0][tid] + pdd[1][tid] + pdd[2][tid] + pdd[3][tid];
        }
    }
}

// ---------------------------------------------------------------------------
// Layer-2 aggregation: one wave per dst node, bf16 g2 gather, f32 weights.
// ---------------------------------------------------------------------------
__global__ __launch_bounds__(256) void agg2_kernel(const int* __restrict__ off,
                                                   const int* __restrict__ col,
                                                   const float* __restrict__ w2,
                                                   const __bf16* __restrict__ g2b,
                                                   const float* __restrict__ as2,
                                                   const float* __restrict__ ad2,
                                                   float* __restrict__ out2, int N) {
    const int w = __builtin_amdgcn_readfirstlane((blockIdx.x * 256 + threadIdx.x) >> 6);
    const int lane = threadIdx.x & 63;
    if (w >= N) return;

    float2 acc = make_float2(0.f, 0.f);
    float z = 0.f;
    {   // self-loop
        const float wt = expf(lrelu(as2[w] + ad2[w]));
        const bf16x2 hv = *(const bf16x2*)&g2b[(size_t)w * EMB + lane * 2];
        acc.x += wt * (float)hv[0]; acc.y += wt * (float)hv[1];
        z += wt;
    }
    const int jb = off[w], je = off[w + 1];
    int j = jb;
    for (; j + 3 < je; j += 4) {
        const int s0 = col[j], s1 = col[j + 1], s2 = col[j + 2], s3 = col[j + 3];
        const float w0 = w2[j], w1 = w2[j + 1], w2v = w2[j + 2], w3 = w2[j + 3];
        const bf16x2 b0 = *(const bf16x2*)&g2b[(size_t)s0 * EMB + lane * 2];
        const bf16x2 b1 = *(const bf16x2*)&g2b[(size_t)s1 * EMB + lane * 2];
        const bf16x2 b2 = *(const bf16x2*)&g2b[(size_t)s2 * EMB + lane * 2];
        const bf16x2 b3 = *(const bf16x2*)&g2b[(size_t)s3 * EMB + lane * 2];
        acc.x += w0 * (float)b0[0] + w1 * (float)b1[0] + w2v * (float)b2[0] + w3 * (float)b3[0];
        acc.y += w0 * (float)b0[1] + w1 * (float)b1[1] + w2v * (float)b2[1] + w3 * (float)b3[1];
        z += (w0 + w1) + (w2v + w3);
    }
    for (; j < je; j++) {
        const int s0 = col[j];
        const float w0 = w2[j];
        const bf16x2 b0 = *(const bf16x2*)&g2b[(size_t)s0 * EMB + lane * 2];
        acc.x += w0 * (float)b0[0]; acc.y += w0 * (float)b0[1];
        z += w0;
    }
    const float inv = 1.f / z;
    float2 o = make_float2(acc.x * inv, acc.y * inv);
    *(float2*)&out2[(size_t)w * EMB + lane * 2] = o;
}

// ---------------------------------------------------------------------------
// Global mean pool (782-block run-length form) + divide.
// ---------------------------------------------------------------------------
__global__ __launch_bounds__(128) void pool_kernel(const float* __restrict__ out2,
                                                   const float* __restrict__ b2,
                                                   const int* __restrict__ batch,
                                                   float* __restrict__ pool,
                                                   float* __restrict__ cnt, int N) {
    const int c = threadIdx.x;
    const int n0 = blockIdx.x * 64;
    const int nend = min(n0 + 64, N);
    const float bias = b2[c];
    float acc = 0.f, cacc = 0.f;
    int curg = batch[n0];
    for (int n = n0; n < nend; n++) {
        const int g = batch[n];
        if (g != curg) {
            atomicAdd(&pool[curg * EMB + c], acc);
            if (c == 0) atomicAdd(&cnt[curg], cacc);
            acc = 0.f; cacc = 0.f; curg = g;
        }
        float v = out2[(size_t)n * EMB + c] + bias;
        v = v > 0.f ? v : expm1f(v);
        acc += v;
        cacc += 1.f;
    }
    atomicAdd(&pool[curg * EMB + c], acc);
    if (c == 0) atomicAdd(&cnt[curg], cacc);
}

__global__ __launch_bounds__(256) void div_kernel(const float* __restrict__ pool,
                                                  const float* __restrict__ cnt,
                                                  float* __restrict__ out) {
    const int i = blockIdx.x * 256 + threadIdx.x;
    out[i] = pool[i] / fmaxf(cnt[i >> 7], 1.f);
}

// ---------------------------------------------------------------------------
extern "C" void kernel_launch(void* const* d_in, const int* in_sizes, int n_in,
                              void* d_out, int out_size, void* d_ws, size_t ws_size,
                              hipStream_t stream) {
    const float* x      = (const float*)d_in[0];
    const int*   ei     = (const int*)d_in[1];
    const int*   batch  = (const int*)d_in[3];
    const float* W1     = (const float*)d_in[4];
    const float* a_src1 = (const float*)d_in[5];
    const float* a_dst1 = (const float*)d_in[6];
    const float* b1     = (const float*)d_in[7];
    const float* W2     = (const float*)d_in[8];
    const float* a_src2 = (const float*)d_in[9];
    const float* a_dst2 = (const float*)d_in[10];
    const float* b2     = (const float*)d_in[11];
    float* out = (float*)d_out;

    const int N = N_NODES, E = N_EDGES;

    size_t cur_off = 0;
    auto carve = [&](size_t bytes) {
        size_t o = cur_off;
        cur_off = (cur_off + bytes + 255) & ~(size_t)255;
        return (char*)d_ws + o;
    };
    // zero-init region: deg + pool + cnt
    int* deg     = (int*)carve((size_t)N * 4);
    float* pool  = (float*)carve((size_t)N_GRAPHS * EMB * 4);
    float* cnt   = (float*)carve((size_t)N_GRAPHS * 4);
    const size_t zero_bytes = cur_off;
    int* curp    = (int*)carve((size_t)N * 4);
    int* partial = (int*)carve((size_t)SCAN_BLOCKS * 4);
    __bf16* B1h  = (__bf16*)carve((size_t)HEADS * W1_FRAG * 2);
    __bf16* B1l  = (__bf16*)carve((size_t)HEADS * W1_FRAG * 2);
    __bf16* B2h  = (__bf16*)carve((size_t)F1 * EMB * 2);
    __bf16* B2l  = (__bf16*)carve((size_t)F1 * EMB * 2);
    __bf16* xb   = (__bf16*)carve((size_t)N * IN_DIM * 2);
    int* off     = (int*)carve((size_t)(N + 1) * 4);
    int* col     = (int*)carve((size_t)E * 4);
    int* rowd    = (int*)carve((size_t)E * 4);
    float4* w4   = (float4*)carve((size_t)E * 16);
    float* w2    = (float*)carve((size_t)E * 4);
    __bf16* aggxh = (__bf16*)carve((size_t)N * HEADS * IN_DIM * 2);
    __bf16* aggxl = (__bf16*)carve((size_t)N * HEADS * IN_DIM * 2);
    __bf16* g2b  = (__bf16*)carve((size_t)N * EMB * 2);
    float* out2  = (float*)carve((size_t)N * EMB * 4);
    float* as1   = (float*)carve((size_t)N * HEADS * 4);
    float* ad1   = (float*)carve((size_t)N * HEADS * 4);
    float* as2   = (float*)carve((size_t)N * 4);
    float* ad2   = (float*)carve((size_t)N * 4);

    hipMemsetAsync(d_ws, 0, zero_bytes, stream);

    prep_kernel<<<DEG_BLOCKS + 32 + XCONV_BLOCKS, 256, 0, stream>>>(
        ei, deg, W1, B1h, B1l, W2, B2h, B2l, x, xb);

    scanA_kernel<<<SCAN_BLOCKS, 256, 0, stream>>>(deg, off, partial, N);
    scanB_kernel<<<1, 256, 0, stream>>>(partial, &off[N]);
    scanC_kernel<<<SCAN_BLOCKS, 256, 0, stream>>>(off, partial, curp, N);

    // gemm1 (x -> as1/ad1), then scatter fused with edge-weight computation
    gemm1_kernel<<<(N + 63) / 64, 256, 0, stream>>>(x, B1h, B1l, a_src1, a_dst1,
                                                    as1, ad1, N);
    scatter_w1_kernel<<<DEG_BLOCKS, 256, 0, stream>>>(ei, off, curp, col, rowd,
                                                      as1, ad1, w4, E);

    agg1x_kernel<<<(N + 3) / 4, 256, 0, stream>>>(off, col, w4, xb, as1, ad1,
                                                  aggxh, aggxl, N);

    // fused: (aggx @ W1 -> ELU -> @ W2) + alpha2; all operands pre-split bf16
    gemm12_kernel<<<(N + 15) / 16, 256, 0, stream>>>(aggxh, aggxl, B1h, B1l, b1,
                                                     B2h, B2l, a_src2, a_dst2,
                                                     g2b, as2, ad2, N);

    w2_kernel<<<DEG_BLOCKS, 256, 0, stream>>>(col, rowd, as2, ad2, w2, E);
    agg2_kernel<<<(N + 3) / 4, 256, 0, stream>>>(off, col, w2, g2b, as2, ad2, out2, N);

    pool_kernel<<<(N + 63) / 64, 128, 0, stream>>>(out2, b2, batch, pool, cnt, N);
    div_kernel<<<(N_GRAPHS * EMB) / 256, 256, 0, stream>>>(pool, cnt, out);
}

// Round 14
// 362.529 us; speedup vs baseline: 1.3399x; 1.0294x over previous
//
#include <hip/hip_runtime.h>
#include <hip/hip_bf16.h>
#include <cstddef>

// Problem constants (fixed-shape problem)
constexpr int N_NODES = 50000;
constexpr int N_EDGES = 800000;
constexpr int IN_DIM  = 128;
constexpr int HID     = 64;
constexpr int HEADS   = 4;
constexpr int F1      = HEADS * HID;  // 256
constexpr int EMB     = 128;
constexpr int N_GRAPHS = 64;

constexpr int DEG_BLOCKS   = (N_EDGES + 255) / 256;          // 3125
constexpr int SCAN_BLOCKS  = (N_NODES + 255) / 256;          // 196
constexpr int GEMM1_BLOCKS = (N_NODES + 63) / 64;            // 782
constexpr int XCONV_BLOCKS = (N_NODES * IN_DIM / 4) / 256;   // 6250 (exact)
// per-head W1 fragment size (NT=4, KK=4): 4*4*64*8 bf16 elements
constexpr int W1_FRAG = 4 * 4 * 64 * 8;                      // 8192
// gemm12 LDS tile stride in bf16 elems: 264*2 = 528 B rows (16 B aligned for
// ds_read_b128; 132 dwords mod 32 = 4 -> ~2-way bank alias, free per m136)
constexpr int LDSB = 264;

typedef __bf16 bf16x8 __attribute__((ext_vector_type(8)));
typedef __bf16 bf16x2 __attribute__((ext_vector_type(2)));
typedef float  f32x4  __attribute__((ext_vector_type(4)));

__device__ __forceinline__ float lrelu(float x) { return x > 0.f ? x : 0.2f * x; }
__device__ __forceinline__ float eluf(float x)  { return x > 0.f ? x : expm1f(x); }

// ---------------------------------------------------------------------------
// Pack a [K x 16*NT] submatrix of B (leading dim ld, origin col0) into
// per-lane MFMA B-fragments, split hi/lo bf16.
// ---------------------------------------------------------------------------
__device__ __forceinline__ void pack_frag(const float* __restrict__ B,
                                          __bf16* __restrict__ hi,
                                          __bf16* __restrict__ lo,
                                          int pblk, int NT, int KK, int ld, int col0) {
    const int gid = pblk * 256 + threadIdx.x;
    if (gid >= NT * KK * 64) return;
    const int lane = gid & 63;
    const int rem  = gid >> 6;
    const int kk   = rem % KK;
    const int t    = rem / KK;
    const int n    = col0 + t * 16 + (lane & 15);
    const int k0   = kk * 32 + (lane >> 4) * 8;
#pragma unroll
    for (int j = 0; j < 8; j++) {
        const float v = B[(size_t)(k0 + j) * ld + n];
        const __bf16 h = (__bf16)v;
        hi[(size_t)gid * 8 + j] = h;
        lo[(size_t)gid * 8 + j] = (__bf16)(v - (float)h);
    }
}

// ---------------------------------------------------------------------------
// prep: [deg histogram | pack W1 | pack W2 | x -> bf16 copy] by block range.
// ---------------------------------------------------------------------------
__global__ __launch_bounds__(256) void prep_kernel(const int* __restrict__ ei,
                                                   int* __restrict__ deg,
                                                   const float* __restrict__ W1,
                                                   __bf16* __restrict__ B1h,
                                                   __bf16* __restrict__ B1l,
                                                   const float* __restrict__ W2,
                                                   __bf16* __restrict__ B2h,
                                                   __bf16* __restrict__ B2l,
                                                   const float* __restrict__ x,
                                                   __bf16* __restrict__ xb) {
    const int b = blockIdx.x;
    if (b < DEG_BLOCKS) {
        const int e = b * 256 + threadIdx.x;
        if (e < N_EDGES) atomicAdd(&deg[ei[N_EDGES + e]], 1);
        return;
    }
    const int pb = b - DEG_BLOCKS;
    if (pb < 16) {
        const int head = pb >> 2;
        pack_frag(W1, B1h + head * W1_FRAG, B1l + head * W1_FRAG,
                  pb & 3, 4, 4, F1, head * HID);
        return;
    }
    if (pb < 32) {
        pack_frag(W2, B2h, B2l, pb - 16, 8, 8, EMB, 0);
        return;
    }
    // x -> bf16 (float4 in, 4x bf16 out)
    const int i = (pb - 32) * 256 + threadIdx.x;  // quad index
    const float4 v = *(const float4*)&x[(size_t)i * 4];
    __bf16 o[4] = {(__bf16)v.x, (__bf16)v.y, (__bf16)v.z, (__bf16)v.w};
    *(ulong1*)&xb[(size_t)i * 4] = *(ulong1*)o;
}

// ---------------------------------------------------------------------------
// 3-phase parallel scan (deg -> off). Phase C also zeroes cur AND fills
// rowd[off[i]..off[i]+deg[i]) = i (coalesced runs — avoids the scattered
// rowd write that was 1/3 of scatter_w1's 103 MB write amplification).
// ---------------------------------------------------------------------------
__global__ __launch_bounds__(256) void scanA_kernel(const int* __restrict__ deg,
                                                    int* __restrict__ off,
                                                    int* __restrict__ partial, int N) {
    __shared__ int sm[256];
    const int t = threadIdx.x;
    const int i = blockIdx.x * 256 + t;
    const int v = (i < N) ? deg[i] : 0;
    sm[t] = v;
    __syncthreads();
    int val = v;
#pragma unroll
    for (int o = 1; o < 256; o <<= 1) {
        const int add = (t >= o) ? sm[t - o] : 0;
        __syncthreads();
        val += add;
        sm[t] = val;
        __syncthreads();
    }
    if (i < N) off[i] = val - v;
    if (t == 255) partial[blockIdx.x] = val;
}

__global__ __launch_bounds__(256) void scanB_kernel(int* __restrict__ partial,
                                                    int* __restrict__ off_last) {
    __shared__ int sm[256];
    const int t = threadIdx.x;
    const int v = (t < SCAN_BLOCKS) ? partial[t] : 0;
    sm[t] = v;
    __syncthreads();
    int val = v;
#pragma unroll
    for (int o = 1; o < 256; o <<= 1) {
        const int add = (t >= o) ? sm[t - o] : 0;
        __syncthreads();
        val += add;
        sm[t] = val;
        __syncthreads();
    }
    if (t < SCAN_BLOCKS) partial[t] = val - v;
    if (t == SCAN_BLOCKS - 1) *off_last = val;
}

__global__ __launch_bounds__(256) void scanC_kernel(int* __restrict__ off,
                                                    const int* __restrict__ partial,
                                                    const int* __restrict__ deg,
                                                    int* __restrict__ cur,
                                                    int* __restrict__ rowd, int N) {
    const int i = blockIdx.x * 256 + threadIdx.x;
    if (i < N) {
        const int o = off[i] + partial[blockIdx.x];
        off[i] = o;
        cur[i] = 0;
        const int d = deg[i];
        for (int j = 0; j < d; j++) rowd[o + j] = i;
    }
}

// ---------------------------------------------------------------------------
// gemm1 body: as1/ad1 = alpha-logits of (x @ W1). No C store.
// ---------------------------------------------------------------------------
__device__ __forceinline__ void gemm1_body(int blk,
        const float* __restrict__ A, const __bf16* __restrict__ Bh,
        const __bf16* __restrict__ Bl, const float* __restrict__ avs,
        const float* __restrict__ avd, float* __restrict__ as_out,
        float* __restrict__ ad_out, int M) {
    constexpr int NT = F1 / 16, KK = IN_DIM / 32, NH = HEADS;
    constexpr int Ncols = NT * 16;
    constexpr int K = KK * 32;
    const int tid  = threadIdx.x;
    const int wave = tid >> 6, lane = tid & 63;
    const int quad = lane >> 4, l16 = lane & 15;
    const int rowA = min(blk * 64 + wave * 16 + l16, M - 1);

    f32x4 acc[NT];
#pragma unroll
    for (int t = 0; t < NT; t++) acc[t] = (f32x4){0.f, 0.f, 0.f, 0.f};

    for (int kk = 0; kk < KK; kk++) {
        const int k0 = kk * 32 + quad * 8;
        float a8[8];
        *(float4*)&a8[0] = *(const float4*)&A[(size_t)rowA * K + k0];
        *(float4*)&a8[4] = *(const float4*)&A[(size_t)rowA * K + k0 + 4];
        bf16x8 ah, al;
#pragma unroll
        for (int j = 0; j < 8; j++) {
            const __bf16 h = (__bf16)a8[j];
            ah[j] = h;
            al[j] = (__bf16)(a8[j] - (float)h);
        }
#pragma unroll
        for (int t = 0; t < NT; t++) {
            const size_t bi = ((size_t)(t * KK + kk) * 64 + lane) * 8;
            bf16x8 bhv = *(const bf16x8*)&Bh[bi];
            bf16x8 blv = *(const bf16x8*)&Bl[bi];
            acc[t] = __builtin_amdgcn_mfma_f32_16x16x32_bf16(ah, bhv, acc[t], 0, 0, 0);
            acc[t] = __builtin_amdgcn_mfma_f32_16x16x32_bf16(al, bhv, acc[t], 0, 0, 0);
            acc[t] = __builtin_amdgcn_mfma_f32_16x16x32_bf16(ah, blv, acc[t], 0, 0, 0);
        }
    }

    const int rowS = blk * 64 + wave * 16 + quad * 4;
#pragma unroll
    for (int r = 0; r < 4; r++) {
        float ps[NH], pd[NH];
#pragma unroll
        for (int h = 0; h < NH; h++) { ps[h] = 0.f; pd[h] = 0.f; }
#pragma unroll
        for (int t = 0; t < NT; t++) {
            const int h = (t * 16) / (Ncols / NH);
            const int col = t * 16 + l16;
            ps[h] += acc[t][r] * avs[col];
            pd[h] += acc[t][r] * avd[col];
        }
#pragma unroll
        for (int o = 1; o < 16; o <<= 1) {
#pragma unroll
            for (int h = 0; h < NH; h++) {
                ps[h] += __shfl_xor(ps[h], o);
                pd[h] += __shfl_xor(pd[h], o);
            }
        }
        const int rr = rowS + r;
        if (l16 == 0 && rr < M) {
#pragma unroll
            for (int h = 0; h < NH; h++) {
                as_out[rr * NH + h] = ps[h];
                ad_out[rr * NH + h] = pd[h];
            }
        }
    }
}

// gemm1 + col-only CSR scatter in one dispatch (independent block ranges;
// the scatter no longer needs as1/ad1 since w4 moved to slot-parallel w1).
__global__ __launch_bounds__(256) void gemm1_scatter_kernel(
        const float* __restrict__ A, const __bf16* __restrict__ Bh,
        const __bf16* __restrict__ Bl, const float* __restrict__ avs,
        const float* __restrict__ avd, float* __restrict__ as_out,
        float* __restrict__ ad_out, int M,
        const int* __restrict__ ei, const int* __restrict__ off,
        int* __restrict__ cur, int* __restrict__ col) {
    if (blockIdx.x < GEMM1_BLOCKS) {
        gemm1_body(blockIdx.x, A, Bh, Bl, avs, avd, as_out, ad_out, M);
        return;
    }
    const int e = (blockIdx.x - GEMM1_BLOCKS) * 256 + threadIdx.x;
    if (e >= N_EDGES) return;
    const int s = ei[e], d = ei[N_EDGES + e];
    col[off[d] + atomicAdd(&cur[d], 1)] = s;
}

// Layer-1 edge weights, slot-parallel: coalesced col/rowd reads, coalesced
// 16 B w4 writes; ad1[rowd[i]] reads are monotone (rowd sorted by slot).
__global__ __launch_bounds__(256) void w1_kernel(const int* __restrict__ col,
                                                 const int* __restrict__ rowd,
                                                 const float* __restrict__ as1,
                                                 const float* __restrict__ ad1,
                                                 float4* __restrict__ w4, int E) {
    const int i = blockIdx.x * 256 + threadIdx.x;
    if (i >= E) return;
    const float4 a = *(const float4*)&as1[col[i] * HEADS];
    const float4 b = *(const float4*)&ad1[rowd[i] * HEADS];
    float4 o;
    o.x = expf(lrelu(a.x + b.x));
    o.y = expf(lrelu(a.y + b.y));
    o.z = expf(lrelu(a.z + b.z));
    o.w = expf(lrelu(a.w + b.w));
    w4[i] = o;
}

// Layer-2 edge weights (one exp per edge instead of 64).
__global__ __launch_bounds__(256) void w2_kernel(const int* __restrict__ col,
                                                 const int* __restrict__ row,
                                                 const float* __restrict__ as2,
                                                 const float* __restrict__ ad2,
                                                 float* __restrict__ w2, int E) {
    const int i = blockIdx.x * 256 + threadIdx.x;
    if (i >= E) return;
    w2[i] = expf(lrelu(as2[col[i]] + ad2[row[i]]));
}

// ---------------------------------------------------------------------------
// Layer-1 x-aggregation: bf16 x gather, f32 accumulate; output pre-split into
// bf16 hi/lo planes so gemm12 loads MFMA A-fragments with ZERO repack VALU.
// ---------------------------------------------------------------------------
__global__ __launch_bounds__(256) void agg1x_kernel(const int* __restrict__ off,
                                                    const int* __restrict__ col,
                                                    const float4* __restrict__ w4,
                                                    const __bf16* __restrict__ xb,
                                                    const float* __restrict__ as1,
                                                    const float* __restrict__ ad1,
                                                    __bf16* __restrict__ aggxh,
                                                    __bf16* __restrict__ aggxl, int N) {
    const int w = __builtin_amdgcn_readfirstlane((blockIdx.x * 256 + threadIdx.x) >> 6);
    const int lane = threadIdx.x & 63;
    if (w >= N) return;

    float2 acc[HEADS];
    float z[HEADS];
#pragma unroll
    for (int h = 0; h < HEADS; h++) { acc[h] = make_float2(0.f, 0.f); z[h] = 0.f; }

    {   // self-loop
        const float4 asv = *(const float4*)&as1[w * HEADS];
        const float4 adv = *(const float4*)&ad1[w * HEADS];
        const bf16x2 xv = *(const bf16x2*)&xb[(size_t)w * IN_DIM + lane * 2];
        const float vx = (float)xv[0], vy = (float)xv[1];
        float ws[HEADS] = {expf(lrelu(asv.x + adv.x)), expf(lrelu(asv.y + adv.y)),
                           expf(lrelu(asv.z + adv.z)), expf(lrelu(asv.w + adv.w))};
#pragma unroll
        for (int h = 0; h < HEADS; h++) {
            acc[h].x += ws[h] * vx; acc[h].y += ws[h] * vy; z[h] += ws[h];
        }
    }
    const int jb = off[w], je = off[w + 1];
    int j = jb;
    for (; j + 3 < je; j += 4) {
        const int s0 = col[j], s1 = col[j + 1], s2 = col[j + 2], s3 = col[j + 3];
        const float4 w0 = w4[j], w1 = w4[j + 1], w2 = w4[j + 2], w3 = w4[j + 3];
        const bf16x2 b0 = *(const bf16x2*)&xb[(size_t)s0 * IN_DIM + lane * 2];
        const bf16x2 b1 = *(const bf16x2*)&xb[(size_t)s1 * IN_DIM + lane * 2];
        const bf16x2 b2 = *(const bf16x2*)&xb[(size_t)s2 * IN_DIM + lane * 2];
        const bf16x2 b3 = *(const bf16x2*)&xb[(size_t)s3 * IN_DIM + lane * 2];
        const float v0x = (float)b0[0], v0y = (float)b0[1];
        const float v1x = (float)b1[0], v1y = (float)b1[1];
        const float v2x = (float)b2[0], v2y = (float)b2[1];
        const float v3x = (float)b3[0], v3y = (float)b3[1];
        acc[0].x += w0.x * v0x + w1.x * v1x + w2.x * v2x + w3.x * v3x;
        acc[0].y += w0.x * v0y + w1.x * v1y + w2.x * v2y + w3.x * v3y;
        acc[1].x += w0.y * v0x + w1.y * v1x + w2.y * v2x + w3.y * v3x;
        acc[1].y += w0.y * v0y + w1.y * v1y + w2.y * v2y + w3.y * v3y;
        acc[2].x += w0.z * v0x + w1.z * v1x + w2.z * v2x + w3.z * v3x;
        acc[2].y += w0.z * v0y + w1.z * v1y + w2.z * v2y + w3.z * v3y;
        acc[3].x += w0.w * v0x + w1.w * v1x + w2.w * v2x + w3.w * v3x;
        acc[3].y += w0.w * v0y + w1.w * v1y + w2.w * v2y + w3.w * v3y;
        z[0] += (w0.x + w1.x) + (w2.x + w3.x);
        z[1] += (w0.y + w1.y) + (w2.y + w3.y);
        z[2] += (w0.z + w1.z) + (w2.z + w3.z);
        z[3] += (w0.w + w1.w) + (w2.w + w3.w);
    }
    for (; j < je; j++) {
        const int s0 = col[j];
        const float4 w0 = w4[j];
        const bf16x2 b0 = *(const bf16x2*)&xb[(size_t)s0 * IN_DIM + lane * 2];
        const float v0x = (float)b0[0], v0y = (float)b0[1];
        acc[0].x += w0.x * v0x; acc[0].y += w0.x * v0y; z[0] += w0.x;
        acc[1].x += w0.y * v0x; acc[1].y += w0.y * v0y; z[1] += w0.y;
        acc[2].x += w0.z * v0x; acc[2].y += w0.z * v0y; z[2] += w0.z;
        acc[3].x += w0.w * v0x; acc[3].y += w0.w * v0y; z[3] += w0.w;
    }
#pragma unroll
    for (int h = 0; h < HEADS; h++) {
        const float inv = 1.f / z[h];
        const float vx = acc[h].x * inv, vy = acc[h].y * inv;
        const __bf16 hx = (__bf16)vx, hy = (__bf16)vy;
        bf16x2 hv = {hx, hy};
        bf16x2 lv = {(__bf16)(vx - (float)hx), (__bf16)(vy - (float)hy)};
        const size_t o = ((size_t)w * HEADS + h) * IN_DIM + lane * 2;
        *(bf16x2*)&aggxh[o] = hv;
        *(bf16x2*)&aggxl[o] = lv;
    }
}

// ---------------------------------------------------------------------------
// FUSED layer-1-reconstruct + layer-2 GEMM, 16 rows/block, 4 waves.
// A-operands (aggx) and the inter-layer LDS tile are pre-split bf16 hi/lo.
// ---------------------------------------------------------------------------
__global__ __launch_bounds__(256) void gemm12_kernel(
        const __bf16* __restrict__ aggxh, const __bf16* __restrict__ aggxl,
        const __bf16* __restrict__ B1h, const __bf16* __restrict__ B1l,
        const float* __restrict__ b1,
        const __bf16* __restrict__ B2h, const __bf16* __restrict__ B2l,
        const float* __restrict__ avs, const float* __restrict__ avd,
        __bf16* __restrict__ g2b, float* __restrict__ as_out,
        float* __restrict__ ad_out, int M) {
    __shared__ __bf16 smh[16 * LDSB];
    __shared__ __bf16 sml[16 * LDSB];
    __shared__ float pps[4][16], pdd[4][16];
    const int tid  = threadIdx.x;
    const int wave = tid >> 6, lane = tid & 63;
    const int quad = lane >> 4, l16 = lane & 15;
    const int row0 = blockIdx.x * 16;
    const int rowA = min(row0 + l16, M - 1);

    // ---- phase 1: this wave's head = `wave`; A-fragments direct from planes
    {
        f32x4 acc1[4];
#pragma unroll
        for (int t = 0; t < 4; t++) acc1[t] = (f32x4){0.f, 0.f, 0.f, 0.f};
        const size_t abase = ((size_t)rowA * HEADS + wave) * IN_DIM;
#pragma unroll
        for (int kk = 0; kk < 4; kk++) {
            const int k0 = kk * 32 + quad * 8;
            bf16x8 ah = *(const bf16x8*)&aggxh[abase + k0];
            bf16x8 al = *(const bf16x8*)&aggxl[abase + k0];
#pragma unroll
            for (int t = 0; t < 4; t++) {
                const size_t bi = (size_t)wave * W1_FRAG +
                                  ((size_t)(t * 4 + kk) * 64 + lane) * 8;
                bf16x8 bhv = *(const bf16x8*)&B1h[bi];
                bf16x8 blv = *(const bf16x8*)&B1l[bi];
                acc1[t] = __builtin_amdgcn_mfma_f32_16x16x32_bf16(ah, bhv, acc1[t], 0, 0, 0);
                acc1[t] = __builtin_amdgcn_mfma_f32_16x16x32_bf16(al, bhv, acc1[t], 0, 0, 0);
                acc1[t] = __builtin_amdgcn_mfma_f32_16x16x32_bf16(ah, blv, acc1[t], 0, 0, 0);
            }
        }
        // ELU(+b1) -> LDS hi/lo planes (split once here, consumed raw below)
#pragma unroll
        for (int t = 0; t < 4; t++) {
            const int c = wave * 64 + t * 16 + l16;
            const float bb = b1[c];
#pragma unroll
            for (int r = 0; r < 4; r++) {
                const float v = eluf(acc1[t][r] + bb);
                const __bf16 hh = (__bf16)v;
                smh[(quad * 4 + r) * LDSB + c] = hh;
                sml[(quad * 4 + r) * LDSB + c] = (__bf16)(v - (float)hh);
            }
        }
    }
    __syncthreads();

    // ---- phase 2: this wave's output cols = tiles {2*wave, 2*wave+1} ----
    f32x4 acc2[2];
#pragma unroll
    for (int t = 0; t < 2; t++) acc2[t] = (f32x4){0.f, 0.f, 0.f, 0.f};
    const int arow = l16 * LDSB;
#pragma unroll
    for (int kk = 0; kk < 8; kk++) {
        const int k0 = kk * 32 + quad * 8;
        bf16x8 ah = *(const bf16x8*)&smh[arow + k0];
        bf16x8 al = *(const bf16x8*)&sml[arow + k0];
#pragma unroll
        for (int tt = 0; tt < 2; tt++) {
            const int t = wave * 2 + tt;
            const size_t bi = ((size_t)(t * 8 + kk) * 64 + lane) * 8;
            bf16x8 bhv = *(const bf16x8*)&B2h[bi];
            bf16x8 blv = *(const bf16x8*)&B2l[bi];
            acc2[tt] = __builtin_amdgcn_mfma_f32_16x16x32_bf16(ah, bhv, acc2[tt], 0, 0, 0);
            acc2[tt] = __builtin_amdgcn_mfma_f32_16x16x32_bf16(al, bhv, acc2[tt], 0, 0, 0);
            acc2[tt] = __builtin_amdgcn_mfma_f32_16x16x32_bf16(ah, blv, acc2[tt], 0, 0, 0);
        }
    }

    // store g2 (bf16) + alpha2 logit partials (f32, exact from acc2)
    const int rowS = row0 + quad * 4;
#pragma unroll
    for (int tt = 0; tt < 2; tt++) {
        const int t = wave * 2 + tt;
#pragma unroll
        for (int r = 0; r < 4; r++) {
            const int rr = rowS + r;
            if (rr < M) g2b[(size_t)rr * EMB + t * 16 + l16] = (__bf16)acc2[tt][r];
        }
    }
#pragma unroll
    for (int r = 0; r < 4; r++) {
        float ps = 0.f, pd = 0.f;
#pragma unroll
        for (int tt = 0; tt < 2; tt++) {
            const int c = (wave * 2 + tt) * 16 + l16;
            ps += acc2[tt][r] * avs[c];
            pd += acc2[tt][r] * avd[c];
        }
#pragma unroll
        for (int o = 1; o < 16; o <<= 1) {
            ps += __shfl_xor(ps, o);
            pd += __shfl_xor(pd, o);
        }
        if (l16 == 0) {
            pps[wave][quad * 4 + r] = ps;
            pdd[wave][quad * 4 + r] = pd;
        }
    }
    __syncthreads();
    if (tid < 16) {
        const int rr = row0 + tid;
        if (rr < M) {
            as_out[rr] = pps[0][tid] + pps[1][tid] + pps[2][tid] + pps[3][tid];
            ad_out[rr] = pdd[0][tid] + pdd[1][tid] + pdd[2][tid] + pdd[3][tid];
        }
    }
}

// ---------------------------------------------------------------------------
// Layer-2 aggregation: one wave per dst node, bf16 g2 gather, f32 weights.
// ---------------------------------------------------------------------------
__global__ __launch_bounds__(256) void agg2_kernel(const int* __restrict__ off,
                                                   const int* __restrict__ col,
                                                   const float* __restrict__ w2,
                                                   const __bf16* __restrict__ g2b,
                                                   const float* __restrict__ as2,
                                                   const float* __restrict__ ad2,
                                                   float* __restrict__ out2, int N) {
    const int w = __builtin_amdgcn_readfirstlane((blockIdx.x * 256 + threadIdx.x) >> 6);
    const int lane = threadIdx.x & 63;
    if (w >= N) return;

    float2 acc = make_float2(0.f, 0.f);
    float z = 0.f;
    {   // self-loop
        const float wt = expf(lrelu(as2[w] + ad2[w]));
        const bf16x2 hv = *(const bf16x2*)&g2b[(size_t)w * EMB + lane * 2];
        acc.x += wt * (float)hv[0]; acc.y += wt * (float)hv[1];
        z += wt;
    }
    const int jb = off[w], je = off[w + 1];
    int j = jb;
    for (; j + 3 < je; j += 4) {
        const int s0 = col[j], s1 = col[j + 1], s2 = col[j + 2], s3 = col[j + 3];
        const float w0 = w2[j], w1 = w2[j + 1], w2v = w2[j + 2], w3 = w2[j + 3];
        const bf16x2 b0 = *(const bf16x2*)&g2b[(size_t)s0 * EMB + lane * 2];
        const bf16x2 b1 = *(const bf16x2*)&g2b[(size_t)s1 * EMB + lane * 2];
        const bf16x2 b2 = *(const bf16x2*)&g2b[(size_t)s2 * EMB + lane * 2];
        const bf16x2 b3 = *(const bf16x2*)&g2b[(size_t)s3 * EMB + lane * 2];
        acc.x += w0 * (float)b0[0] + w1 * (float)b1[0] + w2v * (float)b2[0] + w3 * (float)b3[0];
        acc.y += w0 * (float)b0[1] + w1 * (float)b1[1] + w2v * (float)b2[1] + w3 * (float)b3[1];
        z += (w0 + w1) + (w2v + w3);
    }
    for (; j < je; j++) {
        const int s0 = col[j];
        const float w0 = w2[j];
        const bf16x2 b0 = *(const bf16x2*)&g2b[(size_t)s0 * EMB + lane * 2];
        acc.x += w0 * (float)b0[0]; acc.y += w0 * (float)b0[1];
        z += w0;
    }
    const float inv = 1.f / z;
    float2 o = make_float2(acc.x * inv, acc.y * inv);
    *(float2*)&out2[(size_t)w * EMB + lane * 2] = o;
}

// ---------------------------------------------------------------------------
// Global mean pool (782-block run-length form) + divide.
// ---------------------------------------------------------------------------
__global__ __launch_bounds__(128) void pool_kernel(const float* __restrict__ out2,
                                                   const float* __restrict__ b2,
                                                   const int* __restrict__ batch,
                                                   float* __restrict__ pool,
                                                   float* __restrict__ cnt, int N) {
    const int c = threadIdx.x;
    const int n0 = blockIdx.x * 64;
    const int nend = min(n0 + 64, N);
    const float bias = b2[c];
    float acc = 0.f, cacc = 0.f;
    int curg = batch[n0];
    for (int n = n0; n < nend; n++) {
        const int g = batch[n];
        if (g != curg) {
            atomicAdd(&pool[curg * EMB + c], acc);
            if (c == 0) atomicAdd(&cnt[curg], cacc);
            acc = 0.f; cacc = 0.f; curg = g;
        }
        float v = out2[(size_t)n * EMB + c] + bias;
        v = v > 0.f ? v : expm1f(v);
        acc += v;
        cacc += 1.f;
    }
    atomicAdd(&pool[curg * EMB + c], acc);
    if (c == 0) atomicAdd(&cnt[curg], cacc);
}

__global__ __launch_bounds__(256) void div_kernel(const float* __restrict__ pool,
                                                  const float* __restrict__ cnt,
                                                  float* __restrict__ out) {
    const int i = blockIdx.x * 256 + threadIdx.x;
    out[i] = pool[i] / fmaxf(cnt[i >> 7], 1.f);
}

// ---------------------------------------------------------------------------
extern "C" void kernel_launch(void* const* d_in, const int* in_sizes, int n_in,
                              void* d_out, int out_size, void* d_ws, size_t ws_size,
                              hipStream_t stream) {
    const float* x      = (const float*)d_in[0];
    const int*   ei     = (const int*)d_in[1];
    const int*   batch  = (const int*)d_in[3];
    const float* W1     = (const float*)d_in[4];
    const float* a_src1 = (const float*)d_in[5];
    const float* a_dst1 = (const float*)d_in[6];
    const float* b1     = (const float*)d_in[7];
    const float* W2     = (const float*)d_in[8];
    const float* a_src2 = (const float*)d_in[9];
    const float* a_dst2 = (const float*)d_in[10];
    const float* b2     = (const float*)d_in[11];
    float* out = (float*)d_out;

    const int N = N_NODES, E = N_EDGES;

    size_t cur_off = 0;
    auto carve = [&](size_t bytes) {
        size_t o = cur_off;
        cur_off = (cur_off + bytes + 255) & ~(size_t)255;
        return (char*)d_ws + o;
    };
    // zero-init region: deg + pool + cnt
    int* deg     = (int*)carve((size_t)N * 4);
    float* pool  = (float*)carve((size_t)N_GRAPHS * EMB * 4);
    float* cnt   = (float*)carve((size_t)N_GRAPHS * 4);
    const size_t zero_bytes = cur_off;
    int* curp    = (int*)carve((size_t)N * 4);
    int* partial = (int*)carve((size_t)SCAN_BLOCKS * 4);
    __bf16* B1h  = (__bf16*)carve((size_t)HEADS * W1_FRAG * 2);
    __bf16* B1l  = (__bf16*)carve((size_t)HEADS * W1_FRAG * 2);
    __bf16* B2h  = (__bf16*)carve((size_t)F1 * EMB * 2);
    __bf16* B2l  = (__bf16*)carve((size_t)F1 * EMB * 2);
    __bf16* xb   = (__bf16*)carve((size_t)N * IN_DIM * 2);
    int* off     = (int*)carve((size_t)(N + 1) * 4);
    int* col     = (int*)carve((size_t)E * 4);
    int* rowd    = (int*)carve((size_t)E * 4);
    float4* w4   = (float4*)carve((size_t)E * 16);
    float* w2    = (float*)carve((size_t)E * 4);
    __bf16* aggxh = (__bf16*)carve((size_t)N * HEADS * IN_DIM * 2);
    __bf16* aggxl = (__bf16*)carve((size_t)N * HEADS * IN_DIM * 2);
    __bf16* g2b  = (__bf16*)carve((size_t)N * EMB * 2);
    float* out2  = (float*)carve((size_t)N * EMB * 4);
    float* as1   = (float*)carve((size_t)N * HEADS * 4);
    float* ad1   = (float*)carve((size_t)N * HEADS * 4);
    float* as2   = (float*)carve((size_t)N * 4);
    float* ad2   = (float*)carve((size_t)N * 4);

    hipMemsetAsync(d_ws, 0, zero_bytes, stream);

    prep_kernel<<<DEG_BLOCKS + 32 + XCONV_BLOCKS, 256, 0, stream>>>(
        ei, deg, W1, B1h, B1l, W2, B2h, B2l, x, xb);

    scanA_kernel<<<SCAN_BLOCKS, 256, 0, stream>>>(deg, off, partial, N);
    scanB_kernel<<<1, 256, 0, stream>>>(partial, &off[N]);
    scanC_kernel<<<SCAN_BLOCKS, 256, 0, stream>>>(off, partial, deg, curp, rowd, N);

    // gemm1 (x -> as1/ad1) + col-only scatter, one dispatch
    gemm1_scatter_kernel<<<GEMM1_BLOCKS + DEG_BLOCKS, 256, 0, stream>>>(
        x, B1h, B1l, a_src1, a_dst1, as1, ad1, N, ei, off, curp, col);

    // slot-parallel layer-1 edge weights (coalesced reads/writes)
    w1_kernel<<<DEG_BLOCKS, 256, 0, stream>>>(col, rowd, as1, ad1, w4, E);

    agg1x_kernel<<<(N + 3) / 4, 256, 0, stream>>>(off, col, w4, xb, as1, ad1,
                                                  aggxh, aggxl, N);

    // fused: (aggx @ W1 -> ELU -> @ W2) + alpha2; all operands pre-split bf16
    gemm12_kernel<<<(N + 15) / 16, 256, 0, stream>>>(aggxh, aggxl, B1h, B1l, b1,
                                                     B2h, B2l, a_src2, a_dst2,
                                                     g2b, as2, ad2, N);

    w2_kernel<<<DEG_BLOCKS, 256, 0, stream>>>(col, rowd, as2, ad2, w2, E);
    agg2_kernel<<<(N + 3) / 4, 256, 0, stream>>>(off, col, w2, g2b, as2, ad2, out2, N);

    pool_kernel<<<(N + 63) / 64, 128, 0, stream>>>(out2, b2, batch, pool, cnt, N);
    div_kernel<<<(N_GRAPHS * EMB) / 256, 256, 0, stream>>>(pool, cnt, out);
}